// Round 1
// baseline (9286.089 us; speedup 1.0000x reference)
//
#include <hip/hip_runtime.h>
#include <hip/hip_bf16.h>

constexpr int cB = 32, cS = 128, cT = 64, cH = 512, cH4 = 2048, cVT = 32000, cTM1 = 63;

__device__ __forceinline__ float sigm(float x) { return 1.0f / (1.0f + expf(-x)); }

// ---------------- embeddings ----------------
__global__ __launch_bounds__(128) void k_embed_src(const int* __restrict__ src,
                                                   const float* __restrict__ E,
                                                   float* __restrict__ xs,
                                                   float* __restrict__ neg) {
  int sb = blockIdx.x;            // s*B + b
  int s = sb >> 5, b = sb & 31;
  int tok = src[b * cS + s];
  const float4* erow = (const float4*)(E + (size_t)tok * cH);
  float4* xrow = (float4*)(xs + (size_t)sb * cH);
  xrow[threadIdx.x] = erow[threadIdx.x];
  if (threadIdx.x == 0) neg[b * cS + s] = (tok == 0) ? -1e9f : 0.0f;
}

__global__ __launch_bounds__(128) void k_embed_trg(const int* __restrict__ trg,
                                                   const float* __restrict__ E,
                                                   float* __restrict__ ys) {
  int tb = blockIdx.x;            // t*B + b, t < 63
  int t = tb >> 5, b = tb & 31;
  int tok = trg[b * cT + t];
  const float4* erow = (const float4*)(E + (size_t)tok * cH);
  float4* yrow = (float4*)(ys + (size_t)tb * cH);
  yrow[threadIdx.x] = erow[threadIdx.x];
}

// ---------------- generic fp32 GEMM: C[M,N] = A[M,K] @ W[K,N] + bias[N] ----------------
// tile 128x128, BK=16, 256 threads, 8x8 per thread. Requires N%128==0, K%16==0.
#define GTM 128
#define GTN 128
#define GBK 16
__global__ __launch_bounds__(256) void k_gemm(const float* __restrict__ A,
                                              const float* __restrict__ W,
                                              const float* __restrict__ bias,
                                              float* __restrict__ C,
                                              int M, int K, int N) {
  __shared__ float As[GBK][GTM + 4];
  __shared__ float Bs[GBK][GTN + 4];
  const int tid = threadIdx.x;
  const int tx = tid & 15, ty = tid >> 4;
  const int bm = blockIdx.x * GTM, bn = blockIdx.y * GTN;
  float acc[8][8];
#pragma unroll
  for (int i = 0; i < 8; ++i)
#pragma unroll
    for (int j = 0; j < 8; ++j) acc[i][j] = 0.0f;

  for (int kt = 0; kt < K; kt += GBK) {
    {
      int k4 = (tid & 3) * 4;
      int r0 = tid >> 2;
#pragma unroll
      for (int rr = 0; rr < 2; ++rr) {
        int r = r0 + rr * 64;
        int row = bm + r;
        float4 v = make_float4(0.f, 0.f, 0.f, 0.f);
        if (row < M) v = *(const float4*)(A + (size_t)row * K + kt + k4);
        As[k4 + 0][r] = v.x; As[k4 + 1][r] = v.y; As[k4 + 2][r] = v.z; As[k4 + 3][r] = v.w;
      }
    }
    {
      int n4 = (tid & 31) * 4;
      int kk0 = tid >> 5;
#pragma unroll
      for (int kp = 0; kp < 2; ++kp) {
        int kk = kk0 + kp * 8;
        float4 v = *(const float4*)(W + (size_t)(kt + kk) * N + bn + n4);
        *(float4*)&Bs[kk][n4] = v;
      }
    }
    __syncthreads();
#pragma unroll
    for (int kk = 0; kk < GBK; ++kk) {
      float a[8], bv[8];
#pragma unroll
      for (int i = 0; i < 8; ++i) a[i] = As[kk][ty * 8 + i];
#pragma unroll
      for (int j = 0; j < 8; ++j) bv[j] = Bs[kk][tx * 8 + j];
#pragma unroll
      for (int i = 0; i < 8; ++i)
#pragma unroll
        for (int j = 0; j < 8; ++j) acc[i][j] += a[i] * bv[j];
    }
    __syncthreads();
  }

#pragma unroll
  for (int i = 0; i < 8; ++i) {
    int row = bm + ty * 8 + i;
    if (row < M) {
      float* crow = C + (size_t)row * N + bn + tx * 8;
      const float* brow = bias + bn + tx * 8;
      float4 v0, v1;
      v0.x = acc[i][0] + brow[0]; v0.y = acc[i][1] + brow[1];
      v0.z = acc[i][2] + brow[2]; v0.w = acc[i][3] + brow[3];
      v1.x = acc[i][4] + brow[4]; v1.y = acc[i][5] + brow[5];
      v1.z = acc[i][6] + brow[6]; v1.w = acc[i][7] + brow[7];
      ((float4*)crow)[0] = v0;
      ((float4*)crow)[1] = v1;
    }
  }
}

// ---------------- encoder LSTM step (both directions) ----------------
// grid (16 jgroups, 4 bgroups, 2 dirs), block 256 = 8 b x 32 j
__global__ __launch_bounds__(256) void k_enc_step(
    const float* __restrict__ xWf, const float* __restrict__ xWb,
    const float* __restrict__ Uf, const float* __restrict__ Ub,
    float* __restrict__ hs_f, float* __restrict__ hs_b,
    float* __restrict__ cf, float* __restrict__ cb, int t) {
  const int dir = blockIdx.z;
  const float* xW = dir ? xWb : xWf;
  const float* U = dir ? Ub : Uf;
  float* hs = dir ? hs_b : hs_f;
  float* cst = dir ? cb : cf;
  const int j = (threadIdx.x & 31) + blockIdx.x * 32;
  const int bl = threadIdx.x >> 5;
  const int b = blockIdx.y * 8 + bl;

  __shared__ float hprev[8][cH];
  if (t == 0) {
    for (int idx = threadIdx.x; idx < 8 * cH / 4; idx += 256)
      ((float4*)&hprev[0][0])[idx] = make_float4(0.f, 0.f, 0.f, 0.f);
  } else {
    const float* hbase = hs + ((size_t)(t - 1) * cB + blockIdx.y * 8) * cH;
    for (int idx = threadIdx.x; idx < 8 * cH / 4; idx += 256)
      ((float4*)&hprev[0][0])[idx] = ((const float4*)hbase)[idx];
  }
  __syncthreads();

  const int xrow = (dir ? (cS - 1 - t) : t) * cB + b;
  const float* xwr = xW + (size_t)xrow * cH4;
  float zi = xwr[j], zf = xwr[j + cH], zg = xwr[j + 2 * cH], zo = xwr[j + 3 * cH];
  const float* hp = hprev[bl];
  const float* Uj = U + j;
#pragma unroll 4
  for (int k = 0; k < cH; ++k) {
    float hvv = hp[k];
    const float* ur = Uj + (size_t)k * cH4;
    zi += hvv * ur[0];
    zf += hvv * ur[cH];
    zg += hvv * ur[2 * cH];
    zo += hvv * ur[3 * cH];
  }
  float ig = sigm(zi), fg = sigm(zf), og = sigm(zo), gg = tanhf(zg);
  float cp = 0.f;
  if (t > 0) cp = cst[(size_t)b * cH + j];
  float cn = fg * cp + ig * gg;
  cst[(size_t)b * cH + j] = cn;
  hs[((size_t)t * cB + b) * cH + j] = og * tanhf(cn);
}

// ---------------- concat builder: cat[4160][1024] ----------------
__global__ __launch_bounds__(128) void k_cat(const float* __restrict__ hs_f,
                                             const float* __restrict__ hs_b,
                                             const float* __restrict__ cf,
                                             const float* __restrict__ cb,
                                             float* __restrict__ cat) {
  int r = blockIdx.x;
  const float *pf, *pb;
  if (r < cB * cS) {
    int b = r >> 7, s = r & (cS - 1);
    pf = hs_f + ((size_t)s * cB + b) * cH;
    pb = hs_b + ((size_t)(cS - 1 - s) * cB + b) * cH;
  } else if (r < cB * cS + cB) {
    int b = r - cB * cS;
    pf = hs_f + ((size_t)(cS - 1) * cB + b) * cH;
    pb = hs_b + ((size_t)(cS - 1) * cB + b) * cH;
  } else {
    int b = r - cB * cS - cB;
    pf = cf + (size_t)b * cH;
    pb = cb + (size_t)b * cH;
  }
  float4* crow = (float4*)(cat + (size_t)r * 2 * cH);
  crow[threadIdx.x] = ((const float4*)pf)[threadIdx.x];
  crow[threadIdx.x + cH / 4] = ((const float4*)pb)[threadIdx.x];
}

// ---------------- decoder LSTM step ----------------
// grid (16 jgroups, 4 bgroups), block 256 = 8 b x 32 j
__global__ __launch_bounds__(256) void k_dec_step(
    const float* __restrict__ yW, const float* __restrict__ Ud,
    const float* __restrict__ h_in, int h_stride,
    const float* __restrict__ c_in,
    float* __restrict__ dc, float* __restrict__ dec, int t) {
  const int j = (threadIdx.x & 31) + blockIdx.x * 32;
  const int bl = threadIdx.x >> 5;
  const int b = blockIdx.y * 8 + bl;

  __shared__ float hprev[8][cH];
  for (int idx = threadIdx.x; idx < 8 * cH / 4; idx += 256) {
    int bb = idx >> 7;          // 128 float4 per row
    int k4 = idx & 127;
    ((float4*)&hprev[bb][0])[k4] =
        *(const float4*)(h_in + (size_t)(blockIdx.y * 8 + bb) * h_stride + k4 * 4);
  }
  __syncthreads();

  const float* ywr = yW + ((size_t)t * cB + b) * cH4;
  float zi = ywr[j], zf = ywr[j + cH], zg = ywr[j + 2 * cH], zo = ywr[j + 3 * cH];
  const float* hp = hprev[bl];
  const float* Uj = Ud + j;
#pragma unroll 4
  for (int k = 0; k < cH; ++k) {
    float hvv = hp[k];
    const float* ur = Uj + (size_t)k * cH4;
    zi += hvv * ur[0];
    zf += hvv * ur[cH];
    zg += hvv * ur[2 * cH];
    zo += hvv * ur[3 * cH];
  }
  float ig = sigm(zi), fg = sigm(zf), og = sigm(zo), gg = tanhf(zg);
  float cp = c_in[(size_t)b * cH + j];
  float cn = fg * cp + ig * gg;
  dc[(size_t)b * cH + j] = cn;
  dec[((size_t)b * cTM1 + t) * (2 * cH) + cH + j] = og * tanhf(cn);
}

// ---------------- attention (one block per batch row) ----------------
__global__ __launch_bounds__(256) void k_attn(const float* __restrict__ src_h,
                                              const float* __restrict__ neg,
                                              float* __restrict__ dec, int t) {
  int b = blockIdx.x;
  int tx = threadIdx.x;
  __shared__ float hv[cH];
  __shared__ float part[256];
  __shared__ float sc[cS];
  __shared__ float red[cS];
  float* drow = dec + ((size_t)b * cTM1 + t) * (2 * cH);
  hv[tx] = drow[cH + tx];
  hv[tx + 256] = drow[cH + tx + 256];
  __syncthreads();
  {
    int s = tx >> 1, half = tx & 1;
    const float4* sr = (const float4*)(src_h + ((size_t)b * cS + s) * cH + half * 256);
    const float4* hh = (const float4*)(hv + half * 256);
    float acc = 0.f;
#pragma unroll 8
    for (int k = 0; k < 64; ++k) {
      float4 v = sr[k], h4 = hh[k];
      acc += v.x * h4.x + v.y * h4.y + v.z * h4.z + v.w * h4.w;
    }
    part[tx] = acc;
  }
  __syncthreads();
  if (tx < cS) {
    float s0 = part[2 * tx] + part[2 * tx + 1] + neg[b * cS + tx];
    sc[tx] = s0;
    red[tx] = s0;
  }
  __syncthreads();
  for (int off = 64; off >= 1; off >>= 1) {
    if (tx < off) red[tx] = fmaxf(red[tx], red[tx + off]);
    __syncthreads();
  }
  float mx = red[0];
  __syncthreads();
  float e = 0.f;
  if (tx < cS) { e = expf(sc[tx] - mx); red[tx] = e; }
  __syncthreads();
  for (int off = 64; off >= 1; off >>= 1) {
    if (tx < off) red[tx] += red[tx + off];
    __syncthreads();
  }
  float inv = 1.0f / red[0];
  __syncthreads();
  if (tx < cS) sc[tx] = e * inv;
  __syncthreads();
  float a0 = 0.f, a1 = 0.f;
  for (int s = 0; s < cS; ++s) {
    float w = sc[s];
    const float* sr = src_h + ((size_t)b * cS + s) * cH;
    a0 += w * sr[tx];
    a1 += w * sr[tx + 256];
  }
  drow[tx] = a0;
  drow[tx + 256] = a1;
}

extern "C" void kernel_launch(void* const* d_in, const int* in_sizes, int n_in,
                              void* d_out, int out_size, void* d_ws, size_t ws_size,
                              hipStream_t stream) {
  const int* src = (const int*)d_in[0];
  const int* trg = (const int*)d_in[1];
  const float* E_src = (const float*)d_in[2];
  const float* E_trg = (const float*)d_in[3];
  const float* Wf = (const float*)d_in[4];
  const float* Uf = (const float*)d_in[5];
  const float* bf = (const float*)d_in[6];
  const float* Wb = (const float*)d_in[7];
  const float* Ub = (const float*)d_in[8];
  const float* bb = (const float*)d_in[9];
  const float* Wd = (const float*)d_in[10];
  const float* Ud = (const float*)d_in[11];
  const float* bd = (const float*)d_in[12];
  const float* fcW = (const float*)d_in[13];
  const float* fcb = (const float*)d_in[14];
  const float* clsW = (const float*)d_in[15];
  const float* clsb = (const float*)d_in[16];
  float* out = (float*)d_out;
  float* ws = (float*)d_ws;

  // workspace layout (floats) — total ~36.8M floats (~147 MB)
  float* xs = ws;                                   // [4096][512]  rows s*B+b
  float* xWf = xs + (size_t)4096 * 512;             // [4096][2048]
  float* xWb = xWf + (size_t)4096 * 2048;           // [4096][2048]
  float* hs_f = xWb + (size_t)4096 * 2048;          // [128][32][512]
  float* hs_b = hs_f + (size_t)4096 * 512;          // [128][32][512]
  float* cf = hs_b + (size_t)4096 * 512;            // [32][512]
  float* cb = cf + (size_t)32 * 512;                // [32][512]
  float* cat = cb + (size_t)32 * 512;               // [4160][1024]
  float* fco = cat + (size_t)4160 * 1024;           // [4160][512]  src_h + prev_h + prev_c
  float* neg = fco + (size_t)4160 * 512;            // [32][128]
  float* ys = neg + 4096;                           // [2016][512]  rows t*B+b
  float* yW = ys + (size_t)2016 * 512;              // [2016][2048]
  float* dc = yW + (size_t)2016 * 2048;             // [32][512]
  float* dec = dc + (size_t)32 * 512;               // [32][63][1024] rows b*63+t

  k_embed_src<<<4096, 128, 0, stream>>>(src, E_src, xs, neg);
  k_embed_trg<<<2016, 128, 0, stream>>>(trg, E_trg, ys);

  k_gemm<<<dim3(32, 16), 256, 0, stream>>>(xs, Wf, bf, xWf, 4096, 512, 2048);
  k_gemm<<<dim3(32, 16), 256, 0, stream>>>(xs, Wb, bb, xWb, 4096, 512, 2048);
  k_gemm<<<dim3(16, 16), 256, 0, stream>>>(ys, Wd, bd, yW, 2016, 512, 2048);

  for (int t = 0; t < cS; ++t)
    k_enc_step<<<dim3(16, 4, 2), 256, 0, stream>>>(xWf, xWb, Uf, Ub, hs_f, hs_b, cf, cb, t);

  k_cat<<<4160, 128, 0, stream>>>(hs_f, hs_b, cf, cb, cat);
  k_gemm<<<dim3(33, 4), 256, 0, stream>>>(cat, fcW, fcb, fco, 4160, 1024, 512);

  const float* prev_h = fco + (size_t)4096 * 512;
  const float* prev_c = fco + (size_t)4128 * 512;
  for (int t = 0; t < cTM1; ++t) {
    const float* h_in = t ? (dec + (size_t)(t - 1) * 1024 + 512) : prev_h;
    int hstride = t ? cTM1 * 1024 : 512;
    const float* c_in = t ? (const float*)dc : prev_c;
    k_dec_step<<<dim3(16, 4), 256, 0, stream>>>(yW, Ud, h_in, hstride, c_in, dc, dec, t);
    k_attn<<<32, 256, 0, stream>>>(fco, neg, dec, t);
  }

  k_gemm<<<dim3(16, 250), 256, 0, stream>>>(dec, clsW, clsb, out, 2016, 1024, 32000);
}

// Round 2
// 7602.619 us; speedup vs baseline: 1.2214x; 1.2214x over previous
//
#include <hip/hip_runtime.h>
#include <hip/hip_bf16.h>
#include <stdint.h>

constexpr int cB = 32, cS = 128, cT = 64, cH = 512, cH4 = 2048, cVT = 32000, cTM1 = 63;

typedef __attribute__((ext_vector_type(8))) __bf16 bf16x8;
typedef __attribute__((ext_vector_type(4))) float f32x4;

__device__ __forceinline__ float sigm(float x) { return 1.0f / (1.0f + expf(-x)); }

// ---------------- embeddings ----------------
__global__ __launch_bounds__(128) void k_embed_src(const int* __restrict__ src,
                                                   const float* __restrict__ E,
                                                   float* __restrict__ xs,
                                                   float* __restrict__ neg) {
  int sb = blockIdx.x;            // s*B + b
  int s = sb >> 5, b = sb & 31;
  int tok = src[b * cS + s];
  const float4* erow = (const float4*)(E + (size_t)tok * cH);
  float4* xrow = (float4*)(xs + (size_t)sb * cH);
  xrow[threadIdx.x] = erow[threadIdx.x];
  if (threadIdx.x == 0) neg[b * cS + s] = (tok == 0) ? -1e9f : 0.0f;
}

__global__ __launch_bounds__(128) void k_embed_trg(const int* __restrict__ trg,
                                                   const float* __restrict__ E,
                                                   float* __restrict__ ys) {
  int tb = blockIdx.x;            // t*B + b, t < 63
  int t = tb >> 5, b = tb & 31;
  int tok = trg[b * cT + t];
  const float4* erow = (const float4*)(E + (size_t)tok * cH);
  float4* yrow = (float4*)(ys + (size_t)tb * cH);
  yrow[threadIdx.x] = erow[threadIdx.x];
}

// ---------------- fp32 -> bf16 elementwise with zero tail-pad ----------------
__global__ __launch_bounds__(256) void k_f2b(const float* __restrict__ src,
                                             __hip_bfloat16* __restrict__ dst,
                                             int srcN, int dstN) {
  int i = blockIdx.x * 256 + threadIdx.x;
  if (i < dstN) {
    float v = (i < srcN) ? src[i] : 0.0f;
    dst[i] = __float2bfloat16(v);
  }
}

// ---------------- fp32 [K][N] -> bf16 [N][K] transpose-convert ----------------
__global__ __launch_bounds__(256) void k_f2bT(const float* __restrict__ src,
                                              __hip_bfloat16* __restrict__ dst,
                                              int K, int N) {
  __shared__ float t[32][33];
  int nt = blockIdx.x * 32, kt = blockIdx.y * 32;
  int c = threadIdx.x & 31, r0 = threadIdx.x >> 5;
#pragma unroll
  for (int i = 0; i < 4; ++i) {
    int r = r0 + i * 8;
    t[r][c] = src[(size_t)(kt + r) * N + nt + c];
  }
  __syncthreads();
#pragma unroll
  for (int i = 0; i < 4; ++i) {
    int rr = r0 + i * 8;   // n within tile
    dst[(size_t)(nt + rr) * K + kt + c] = __float2bfloat16(t[c][rr]);
  }
}

// ---------------- bf16 MFMA GEMM: C[M,N] = A[M,K] @ Bt[N,K]^T + bias ----------------
// 128x128 tile, BK=64, 256 threads (4 waves 2x2, each 64x64 via 4x4 16x16 frags).
// A rows must be allocated/zero-padded up to 128-multiple; N,K multiples of 128/64.
__global__ __launch_bounds__(256) void k_bgemm(const __hip_bfloat16* __restrict__ A,
                                               const __hip_bfloat16* __restrict__ Bt,
                                               const float* __restrict__ bias,
                                               float* __restrict__ C,
                                               int M, int K, int N) {
  __shared__ __hip_bfloat16 As[128 * 64];
  __shared__ __hip_bfloat16 Bs[128 * 64];
  const int tid = threadIdx.x;
  const int lane = tid & 63;
  const int wave = tid >> 6;
  const int wr = wave >> 1, wc = wave & 1;
  const int bm = blockIdx.x * 128, bn = blockIdx.y * 128;

  f32x4 acc[4][4] = {};

  const int srow = lane >> 3;          // 0..7 row within 8-row chunk
  const int scol = (lane & 7) * 8;     // k element offset within 64

  for (int kt = 0; kt < K; kt += 64) {
#pragma unroll
    for (int i = 0; i < 4; ++i) {
      int c = wave * 4 + i;            // chunk 0..15, rows c*8..c*8+7
      const __hip_bfloat16* ga = A + (size_t)(bm + c * 8 + srow) * K + kt + scol;
      __builtin_amdgcn_global_load_lds(
          (const __attribute__((address_space(1))) uint32_t*)ga,
          (__attribute__((address_space(3))) uint32_t*)(As + c * 512), 16, 0, 0);
      const __hip_bfloat16* gb = Bt + (size_t)(bn + c * 8 + srow) * K + kt + scol;
      __builtin_amdgcn_global_load_lds(
          (const __attribute__((address_space(1))) uint32_t*)gb,
          (__attribute__((address_space(3))) uint32_t*)(Bs + c * 512), 16, 0, 0);
    }
    __syncthreads();   // compiler drains vmcnt before barrier

#pragma unroll
    for (int kk = 0; kk < 64; kk += 32) {
      const int ko = kk + (lane >> 4) * 8;
      bf16x8 a[4], b[4];
      const int ar = wr * 64 + (lane & 15);
#pragma unroll
      for (int m = 0; m < 4; ++m)
        a[m] = *(const bf16x8*)(As + (size_t)(ar + m * 16) * 64 + ko);
      const int br = wc * 64 + (lane & 15);
#pragma unroll
      for (int n = 0; n < 4; ++n)
        b[n] = *(const bf16x8*)(Bs + (size_t)(br + n * 16) * 64 + ko);
#pragma unroll
      for (int m = 0; m < 4; ++m)
#pragma unroll
        for (int n = 0; n < 4; ++n)
          acc[m][n] = __builtin_amdgcn_mfma_f32_16x16x32_bf16(a[m], b[n], acc[m][n], 0, 0, 0);
    }
    __syncthreads();
  }

  // C/D layout: col = lane&15, row = (lane>>4)*4 + reg   [m89/m91 verified]
#pragma unroll
  for (int m = 0; m < 4; ++m) {
    const int row0 = bm + wr * 64 + m * 16 + (lane >> 4) * 4;
#pragma unroll
    for (int n = 0; n < 4; ++n) {
      const int col = bn + wc * 64 + n * 16 + (lane & 15);
      const float bv = bias[col];
#pragma unroll
      for (int r = 0; r < 4; ++r) {
        const int row = row0 + r;
        if (row < M) C[(size_t)row * N + col] = acc[m][n][r] + bv;
      }
    }
  }
}

// ---------------- generic fp32 GEMM (kept for fc): C[M,N]=A@W+bias ----------------
#define GTM 128
#define GTN 128
#define GBK 16
__global__ __launch_bounds__(256) void k_gemm(const float* __restrict__ A,
                                              const float* __restrict__ W,
                                              const float* __restrict__ bias,
                                              float* __restrict__ C,
                                              int M, int K, int N) {
  __shared__ float As[GBK][GTM + 4];
  __shared__ float Bs[GBK][GTN + 4];
  const int tid = threadIdx.x;
  const int tx = tid & 15, ty = tid >> 4;
  const int bm = blockIdx.x * GTM, bn = blockIdx.y * GTN;
  float acc[8][8];
#pragma unroll
  for (int i = 0; i < 8; ++i)
#pragma unroll
    for (int j = 0; j < 8; ++j) acc[i][j] = 0.0f;

  for (int kt = 0; kt < K; kt += GBK) {
    {
      int k4 = (tid & 3) * 4;
      int r0 = tid >> 2;
#pragma unroll
      for (int rr = 0; rr < 2; ++rr) {
        int r = r0 + rr * 64;
        int row = bm + r;
        float4 v = make_float4(0.f, 0.f, 0.f, 0.f);
        if (row < M) v = *(const float4*)(A + (size_t)row * K + kt + k4);
        As[k4 + 0][r] = v.x; As[k4 + 1][r] = v.y; As[k4 + 2][r] = v.z; As[k4 + 3][r] = v.w;
      }
    }
    {
      int n4 = (tid & 31) * 4;
      int kk0 = tid >> 5;
#pragma unroll
      for (int kp = 0; kp < 2; ++kp) {
        int kk = kk0 + kp * 8;
        float4 v = *(const float4*)(W + (size_t)(kt + kk) * N + bn + n4);
        *(float4*)&Bs[kk][n4] = v;
      }
    }
    __syncthreads();
#pragma unroll
    for (int kk = 0; kk < GBK; ++kk) {
      float a[8], bv[8];
#pragma unroll
      for (int i = 0; i < 8; ++i) a[i] = As[kk][ty * 8 + i];
#pragma unroll
      for (int j = 0; j < 8; ++j) bv[j] = Bs[kk][tx * 8 + j];
#pragma unroll
      for (int i = 0; i < 8; ++i)
#pragma unroll
        for (int j = 0; j < 8; ++j) acc[i][j] += a[i] * bv[j];
    }
    __syncthreads();
  }

#pragma unroll
  for (int i = 0; i < 8; ++i) {
    int row = bm + ty * 8 + i;
    if (row < M) {
      float* crow = C + (size_t)row * N + bn + tx * 8;
      const float* brow = bias + bn + tx * 8;
      float4 v0, v1;
      v0.x = acc[i][0] + brow[0]; v0.y = acc[i][1] + brow[1];
      v0.z = acc[i][2] + brow[2]; v0.w = acc[i][3] + brow[3];
      v1.x = acc[i][4] + brow[4]; v1.y = acc[i][5] + brow[5];
      v1.z = acc[i][6] + brow[6]; v1.w = acc[i][7] + brow[7];
      ((float4*)crow)[0] = v0;
      ((float4*)crow)[1] = v1;
    }
  }
}

// ---------------- encoder LSTM step (both directions) ----------------
__global__ __launch_bounds__(256) void k_enc_step(
    const float* __restrict__ xWf, const float* __restrict__ xWb,
    const float* __restrict__ Uf, const float* __restrict__ Ub,
    float* __restrict__ hs_f, float* __restrict__ hs_b,
    float* __restrict__ cf, float* __restrict__ cb, int t) {
  const int dir = blockIdx.z;
  const float* xW = dir ? xWb : xWf;
  const float* U = dir ? Ub : Uf;
  float* hs = dir ? hs_b : hs_f;
  float* cst = dir ? cb : cf;
  const int j = (threadIdx.x & 31) + blockIdx.x * 32;
  const int bl = threadIdx.x >> 5;
  const int b = blockIdx.y * 8 + bl;

  __shared__ float hprev[8][cH];
  if (t == 0) {
    for (int idx = threadIdx.x; idx < 8 * cH / 4; idx += 256)
      ((float4*)&hprev[0][0])[idx] = make_float4(0.f, 0.f, 0.f, 0.f);
  } else {
    const float* hbase = hs + ((size_t)(t - 1) * cB + blockIdx.y * 8) * cH;
    for (int idx = threadIdx.x; idx < 8 * cH / 4; idx += 256)
      ((float4*)&hprev[0][0])[idx] = ((const float4*)hbase)[idx];
  }
  __syncthreads();

  const int xrow = (dir ? (cS - 1 - t) : t) * cB + b;
  const float* xwr = xW + (size_t)xrow * cH4;
  float zi = xwr[j], zf = xwr[j + cH], zg = xwr[j + 2 * cH], zo = xwr[j + 3 * cH];
  const float* hp = hprev[bl];
  const float* Uj = U + j;
#pragma unroll 4
  for (int k = 0; k < cH; ++k) {
    float hvv = hp[k];
    const float* ur = Uj + (size_t)k * cH4;
    zi += hvv * ur[0];
    zf += hvv * ur[cH];
    zg += hvv * ur[2 * cH];
    zo += hvv * ur[3 * cH];
  }
  float ig = sigm(zi), fg = sigm(zf), og = sigm(zo), gg = tanhf(zg);
  float cp = 0.f;
  if (t > 0) cp = cst[(size_t)b * cH + j];
  float cn = fg * cp + ig * gg;
  cst[(size_t)b * cH + j] = cn;
  hs[((size_t)t * cB + b) * cH + j] = og * tanhf(cn);
}

// ---------------- concat builder: cat[4160][1024] ----------------
__global__ __launch_bounds__(128) void k_cat(const float* __restrict__ hs_f,
                                             const float* __restrict__ hs_b,
                                             const float* __restrict__ cf,
                                             const float* __restrict__ cb,
                                             float* __restrict__ cat) {
  int r = blockIdx.x;
  const float *pf, *pb;
  if (r < cB * cS) {
    int b = r >> 7, s = r & (cS - 1);
    pf = hs_f + ((size_t)s * cB + b) * cH;
    pb = hs_b + ((size_t)(cS - 1 - s) * cB + b) * cH;
  } else if (r < cB * cS + cB) {
    int b = r - cB * cS;
    pf = hs_f + ((size_t)(cS - 1) * cB + b) * cH;
    pb = hs_b + ((size_t)(cS - 1) * cB + b) * cH;
  } else {
    int b = r - cB * cS - cB;
    pf = cf + (size_t)b * cH;
    pb = cb + (size_t)b * cH;
  }
  float4* crow = (float4*)(cat + (size_t)r * 2 * cH);
  crow[threadIdx.x] = ((const float4*)pf)[threadIdx.x];
  crow[threadIdx.x + cH / 4] = ((const float4*)pb)[threadIdx.x];
}

// ---------------- decoder LSTM step ----------------
__global__ __launch_bounds__(256) void k_dec_step(
    const float* __restrict__ yW, const float* __restrict__ Ud,
    const float* __restrict__ h_in, int h_stride,
    const float* __restrict__ c_in,
    float* __restrict__ dc, float* __restrict__ dec, int t) {
  const int j = (threadIdx.x & 31) + blockIdx.x * 32;
  const int bl = threadIdx.x >> 5;
  const int b = blockIdx.y * 8 + bl;

  __shared__ float hprev[8][cH];
  for (int idx = threadIdx.x; idx < 8 * cH / 4; idx += 256) {
    int bb = idx >> 7;
    int k4 = idx & 127;
    ((float4*)&hprev[bb][0])[k4] =
        *(const float4*)(h_in + (size_t)(blockIdx.y * 8 + bb) * h_stride + k4 * 4);
  }
  __syncthreads();

  const float* ywr = yW + ((size_t)t * cB + b) * cH4;
  float zi = ywr[j], zf = ywr[j + cH], zg = ywr[j + 2 * cH], zo = ywr[j + 3 * cH];
  const float* hp = hprev[bl];
  const float* Uj = Ud + j;
#pragma unroll 4
  for (int k = 0; k < cH; ++k) {
    float hvv = hp[k];
    const float* ur = Uj + (size_t)k * cH4;
    zi += hvv * ur[0];
    zf += hvv * ur[cH];
    zg += hvv * ur[2 * cH];
    zo += hvv * ur[3 * cH];
  }
  float ig = sigm(zi), fg = sigm(zf), og = sigm(zo), gg = tanhf(zg);
  float cp = c_in[(size_t)b * cH + j];
  float cn = fg * cp + ig * gg;
  dc[(size_t)b * cH + j] = cn;
  dec[((size_t)b * cTM1 + t) * (2 * cH) + cH + j] = og * tanhf(cn);
}

// ---------------- attention (one block per batch row) ----------------
__global__ __launch_bounds__(256) void k_attn(const float* __restrict__ src_h,
                                              const float* __restrict__ neg,
                                              float* __restrict__ dec, int t) {
  int b = blockIdx.x;
  int tx = threadIdx.x;
  __shared__ float hv[cH];
  __shared__ float part[256];
  __shared__ float sc[cS];
  __shared__ float red[cS];
  float* drow = dec + ((size_t)b * cTM1 + t) * (2 * cH);
  hv[tx] = drow[cH + tx];
  hv[tx + 256] = drow[cH + tx + 256];
  __syncthreads();
  {
    int s = tx >> 1, half = tx & 1;
    const float4* sr = (const float4*)(src_h + ((size_t)b * cS + s) * cH + half * 256);
    const float4* hh = (const float4*)(hv + half * 256);
    float acc = 0.f;
#pragma unroll 8
    for (int k = 0; k < 64; ++k) {
      float4 v = sr[k], h4 = hh[k];
      acc += v.x * h4.x + v.y * h4.y + v.z * h4.z + v.w * h4.w;
    }
    part[tx] = acc;
  }
  __syncthreads();
  if (tx < cS) {
    float s0 = part[2 * tx] + part[2 * tx + 1] + neg[b * cS + tx];
    sc[tx] = s0;
    red[tx] = s0;
  }
  __syncthreads();
  for (int off = 64; off >= 1; off >>= 1) {
    if (tx < off) red[tx] = fmaxf(red[tx], red[tx + off]);
    __syncthreads();
  }
  float mx = red[0];
  __syncthreads();
  float e = 0.f;
  if (tx < cS) { e = expf(sc[tx] - mx); red[tx] = e; }
  __syncthreads();
  for (int off = 64; off >= 1; off >>= 1) {
    if (tx < off) red[tx] += red[tx + off];
    __syncthreads();
  }
  float inv = 1.0f / red[0];
  __syncthreads();
  if (tx < cS) sc[tx] = e * inv;
  __syncthreads();
  float a0 = 0.f, a1 = 0.f;
  for (int s = 0; s < cS; ++s) {
    float w = sc[s];
    const float* sr = src_h + ((size_t)b * cS + s) * cH;
    a0 += w * sr[tx];
    a1 += w * sr[tx + 256];
  }
  drow[tx] = a0;
  drow[tx + 256] = a1;
}

extern "C" void kernel_launch(void* const* d_in, const int* in_sizes, int n_in,
                              void* d_out, int out_size, void* d_ws, size_t ws_size,
                              hipStream_t stream) {
  const int* src = (const int*)d_in[0];
  const int* trg = (const int*)d_in[1];
  const float* E_src = (const float*)d_in[2];
  const float* E_trg = (const float*)d_in[3];
  const float* Wf = (const float*)d_in[4];
  const float* Uf = (const float*)d_in[5];
  const float* bf = (const float*)d_in[6];
  const float* Wb = (const float*)d_in[7];
  const float* Ub = (const float*)d_in[8];
  const float* bb = (const float*)d_in[9];
  const float* Wd = (const float*)d_in[10];
  const float* Ud = (const float*)d_in[11];
  const float* bd = (const float*)d_in[12];
  const float* fcW = (const float*)d_in[13];
  const float* fcb = (const float*)d_in[14];
  const float* clsW = (const float*)d_in[15];
  const float* clsb = (const float*)d_in[16];
  float* out = (float*)d_out;
  float* ws = (float*)d_ws;

  // workspace layout (float units) — same footprint that passed in R1 (~143 MB)
  float* xs = ws;                                   // [4096][512]
  float* xWf = xs + (size_t)4096 * 512;             // [4096][2048]
  float* xWb = xWf + (size_t)4096 * 2048;           // [4096][2048]
  float* hs_f = xWb + (size_t)4096 * 2048;          // [128][32][512]
  float* hs_b = hs_f + (size_t)4096 * 512;          // [128][32][512]
  float* cf = hs_b + (size_t)4096 * 512;            // [32][512]
  float* cb = cf + (size_t)32 * 512;                // [32][512]
  float* cat = cb + (size_t)32 * 512;               // [4160][1024]
  float* fco = cat + (size_t)4160 * 1024;           // [4160][512]
  float* neg = fco + (size_t)4160 * 512;            // [32][128]
  float* ys = neg + 4096;                           // [2016][512]
  float* yW = ys + (size_t)2016 * 512;              // [2016][2048]
  float* dc = yW + (size_t)2016 * 2048;             // [32][512]
  float* dec = dc + (size_t)32 * 512;               // [32][63][1024]

  // bf16 aliases over dead regions:
  // conv zone (pre-encoder) lives in cat region; clsWt over xWf/xWb (post-encoder);
  // dec_bf over xs (post input-GEMMs).
  __hip_bfloat16* xs_bf = (__hip_bfloat16*)(cat);                       // 4096x512
  __hip_bfloat16* ys_bf = (__hip_bfloat16*)(cat + 1048576);             // 2048x512 (padded)
  __hip_bfloat16* Wtf = (__hip_bfloat16*)(cat + 1572864);               // 2048x512
  __hip_bfloat16* Wtb = (__hip_bfloat16*)(cat + 2097152);               // 2048x512
  __hip_bfloat16* Wtd = (__hip_bfloat16*)(cat + 2621440);               // 2048x512
  __hip_bfloat16* clsWt = (__hip_bfloat16*)(xWf);                       // 32000x1024
  __hip_bfloat16* dec_bf = (__hip_bfloat16*)(xs);                       // 2048x1024 (padded)

  k_embed_src<<<4096, 128, 0, stream>>>(src, E_src, xs, neg);
  k_embed_trg<<<2016, 128, 0, stream>>>(trg, E_trg, ys);

  // convert inputs + weights for MFMA projections
  k_f2b<<<8192, 256, 0, stream>>>(xs, xs_bf, 4096 * 512, 4096 * 512);
  k_f2b<<<4096, 256, 0, stream>>>(ys, ys_bf, 2016 * 512, 2048 * 512);
  k_f2bT<<<dim3(64, 16), 256, 0, stream>>>(Wf, Wtf, 512, 2048);
  k_f2bT<<<dim3(64, 16), 256, 0, stream>>>(Wb, Wtb, 512, 2048);
  k_f2bT<<<dim3(64, 16), 256, 0, stream>>>(Wd, Wtd, 512, 2048);

  // input projections via MFMA (fp32 out)
  k_bgemm<<<dim3(32, 16), 256, 0, stream>>>(xs_bf, Wtf, bf, xWf, 4096, 512, 2048);
  k_bgemm<<<dim3(32, 16), 256, 0, stream>>>(xs_bf, Wtb, bb, xWb, 4096, 512, 2048);
  k_bgemm<<<dim3(16, 16), 256, 0, stream>>>(ys_bf, Wtd, bd, yW, 2016, 512, 2048);

  for (int t = 0; t < cS; ++t)
    k_enc_step<<<dim3(16, 4, 2), 256, 0, stream>>>(xWf, xWb, Uf, Ub, hs_f, hs_b, cf, cb, t);

  k_cat<<<4160, 128, 0, stream>>>(hs_f, hs_b, cf, cb, cat);
  k_gemm<<<dim3(33, 4), 256, 0, stream>>>(cat, fcW, fcb, fco, 4160, 1024, 512);

  // classifier weight transpose-convert (xWf/xWb dead now)
  k_f2bT<<<dim3(1000, 32), 256, 0, stream>>>(clsW, clsWt, 1024, 32000);

  const float* prev_h = fco + (size_t)4096 * 512;
  const float* prev_c = fco + (size_t)4128 * 512;
  for (int t = 0; t < cTM1; ++t) {
    const float* h_in = t ? (dec + (size_t)(t - 1) * 1024 + 512) : prev_h;
    int hstride = t ? cTM1 * 1024 : 512;
    const float* c_in = t ? (const float*)dc : prev_c;
    k_dec_step<<<dim3(16, 4), 256, 0, stream>>>(yW, Ud, h_in, hstride, c_in, dc, dec, t);
    k_attn<<<32, 256, 0, stream>>>(fco, neg, dec, t);
  }

  // classifier via MFMA
  k_f2b<<<8192, 256, 0, stream>>>(dec, dec_bf, 2016 * 1024, 2048 * 1024);
  k_bgemm<<<dim3(16, 250), 256, 0, stream>>>(dec_bf, clsWt, clsb, out, 2016, 1024, 32000);
}

// Round 3
// 7037.319 us; speedup vs baseline: 1.3195x; 1.0803x over previous
//
#include <hip/hip_runtime.h>
#include <hip/hip_bf16.h>
#include <stdint.h>

constexpr int cB = 32, cS = 128, cT = 64, cH = 512, cH4 = 2048, cVT = 32000, cTM1 = 63;

typedef __attribute__((ext_vector_type(8))) __bf16 bf16x8;
typedef __attribute__((ext_vector_type(4))) float f32x4;

__device__ __forceinline__ float sigm(float x) { return 1.0f / (1.0f + expf(-x)); }

// ---------------- embeddings ----------------
__global__ __launch_bounds__(128) void k_embed_src(const int* __restrict__ src,
                                                   const float* __restrict__ E,
                                                   float* __restrict__ xs,
                                                   float* __restrict__ neg) {
  int sb = blockIdx.x;            // s*B + b
  int s = sb >> 5, b = sb & 31;
  int tok = src[b * cS + s];
  const float4* erow = (const float4*)(E + (size_t)tok * cH);
  float4* xrow = (float4*)(xs + (size_t)sb * cH);
  xrow[threadIdx.x] = erow[threadIdx.x];
  if (threadIdx.x == 0) neg[b * cS + s] = (tok == 0) ? -1e9f : 0.0f;
}

__global__ __launch_bounds__(128) void k_embed_trg(const int* __restrict__ trg,
                                                   const float* __restrict__ E,
                                                   float* __restrict__ ys) {
  int tb = blockIdx.x;            // t*B + b, t < 63
  int t = tb >> 5, b = tb & 31;
  int tok = trg[b * cT + t];
  const float4* erow = (const float4*)(E + (size_t)tok * cH);
  float4* yrow = (float4*)(ys + (size_t)tb * cH);
  yrow[threadIdx.x] = erow[threadIdx.x];
}

// ---------------- fp32 -> bf16 elementwise with zero tail-pad ----------------
__global__ __launch_bounds__(256) void k_f2b(const float* __restrict__ src,
                                             __hip_bfloat16* __restrict__ dst,
                                             int srcN, int dstN) {
  int i = blockIdx.x * 256 + threadIdx.x;
  if (i < dstN) {
    float v = (i < srcN) ? src[i] : 0.0f;
    dst[i] = __float2bfloat16(v);
  }
}

// ---------------- fp32 [K][N] -> bf16 [N][K] transpose-convert ----------------
// gi=1: additionally permute output row n -> (n&511)*4 + (n>>9)  (gate interleave)
__global__ __launch_bounds__(256) void k_f2bT(const float* __restrict__ src,
                                              __hip_bfloat16* __restrict__ dst,
                                              int K, int N, int gi) {
  __shared__ float t[32][33];
  int nt = blockIdx.x * 32, kt = blockIdx.y * 32;
  int c = threadIdx.x & 31, r0 = threadIdx.x >> 5;
#pragma unroll
  for (int i = 0; i < 4; ++i) {
    int r = r0 + i * 8;
    t[r][c] = src[(size_t)(kt + r) * N + nt + c];
  }
  __syncthreads();
#pragma unroll
  for (int i = 0; i < 4; ++i) {
    int row = nt + r0 + i * 8;   // n within matrix
    int pr = gi ? (((row & 511) << 2) | (row >> 9)) : row;
    dst[(size_t)pr * K + kt + c] = __float2bfloat16(t[c][r0 + i * 8]);
  }
}

// ---------------- bias gate-interleave: out[j*4+g] = in[g*512+j] ----------------
__global__ __launch_bounds__(256) void k_permb(const float* __restrict__ in,
                                               float* __restrict__ out) {
  int i = blockIdx.x * 256 + threadIdx.x;   // 0..2047
  out[i] = in[(i & 3) * 512 + (i >> 2)];
}

// ---------------- U[512][2048] -> Ux[k][j][4] fp32 gate-interleaved ----------------
__global__ __launch_bounds__(256) void k_prepU(const float* __restrict__ U,
                                               float* __restrict__ Ux) {
  int idx = blockIdx.x * 256 + threadIdx.x;   // 0..262143
  int k = idx >> 9, j = idx & 511;
  float4 v;
  v.x = U[(size_t)k * 2048 + j];
  v.y = U[(size_t)k * 2048 + 512 + j];
  v.z = U[(size_t)k * 2048 + 1024 + j];
  v.w = U[(size_t)k * 2048 + 1536 + j];
  ((float4*)Ux)[idx] = v;
}

// ---------------- bf16 MFMA GEMM: C[M,N] = A[M,K] @ Bt[N,K]^T + bias ----------------
__global__ __launch_bounds__(256) void k_bgemm(const __hip_bfloat16* __restrict__ A,
                                               const __hip_bfloat16* __restrict__ Bt,
                                               const float* __restrict__ bias,
                                               float* __restrict__ C,
                                               int M, int K, int N) {
  __shared__ __hip_bfloat16 As[128 * 64];
  __shared__ __hip_bfloat16 Bs[128 * 64];
  const int tid = threadIdx.x;
  const int lane = tid & 63;
  const int wave = tid >> 6;
  const int wr = wave >> 1, wc = wave & 1;
  const int bm = blockIdx.x * 128, bn = blockIdx.y * 128;

  f32x4 acc[4][4] = {};

  const int srow = lane >> 3;
  const int scol = (lane & 7) * 8;

  for (int kt = 0; kt < K; kt += 64) {
#pragma unroll
    for (int i = 0; i < 4; ++i) {
      int c = wave * 4 + i;
      const __hip_bfloat16* ga = A + (size_t)(bm + c * 8 + srow) * K + kt + scol;
      __builtin_amdgcn_global_load_lds(
          (const __attribute__((address_space(1))) uint32_t*)ga,
          (__attribute__((address_space(3))) uint32_t*)(As + c * 512), 16, 0, 0);
      const __hip_bfloat16* gb = Bt + (size_t)(bn + c * 8 + srow) * K + kt + scol;
      __builtin_amdgcn_global_load_lds(
          (const __attribute__((address_space(1))) uint32_t*)gb,
          (__attribute__((address_space(3))) uint32_t*)(Bs + c * 512), 16, 0, 0);
    }
    __syncthreads();

#pragma unroll
    for (int kk = 0; kk < 64; kk += 32) {
      const int ko = kk + (lane >> 4) * 8;
      bf16x8 a[4], b[4];
      const int ar = wr * 64 + (lane & 15);
#pragma unroll
      for (int m = 0; m < 4; ++m)
        a[m] = *(const bf16x8*)(As + (size_t)(ar + m * 16) * 64 + ko);
      const int br = wc * 64 + (lane & 15);
#pragma unroll
      for (int n = 0; n < 4; ++n)
        b[n] = *(const bf16x8*)(Bs + (size_t)(br + n * 16) * 64 + ko);
#pragma unroll
      for (int m = 0; m < 4; ++m)
#pragma unroll
        for (int n = 0; n < 4; ++n)
          acc[m][n] = __builtin_amdgcn_mfma_f32_16x16x32_bf16(a[m], b[n], acc[m][n], 0, 0, 0);
    }
    __syncthreads();
  }

#pragma unroll
  for (int m = 0; m < 4; ++m) {
    const int row0 = bm + wr * 64 + m * 16 + (lane >> 4) * 4;
#pragma unroll
    for (int n = 0; n < 4; ++n) {
      const int col = bn + wc * 64 + n * 16 + (lane & 15);
      const float bv = bias[col];
#pragma unroll
      for (int r = 0; r < 4; ++r) {
        const int row = row0 + r;
        if (row < M) C[(size_t)row * N + col] = acc[m][n][r] + bv;
      }
    }
  }
}

// ---------------- fused encoder: both directions, all 128 steps ----------------
// 32 blocks: XCDs 0-3 run dir0, 4-7 dir1 (L2 holds one dir's Ux). 512 thr, 2 batches.
__global__ __launch_bounds__(512) void k_enc_fused(
    const float* __restrict__ xWf, const float* __restrict__ xWb,
    const float* __restrict__ Uxf, const float* __restrict__ Uxb,
    float* __restrict__ hs_f, float* __restrict__ hs_b,
    float* __restrict__ cf, float* __restrict__ cb) {
  const int bid = blockIdx.x;
  const int xcd = bid & 7, slot = bid >> 3;
  const int dir = xcd >> 2;
  const int pair = (xcd & 3) + slot * 4;      // 0..15
  const int b0 = pair * 2;
  const float* xW = dir ? xWb : xWf;
  const float4* Ux = (const float4*)(dir ? Uxb : Uxf);
  float* hs = dir ? hs_b : hs_f;
  float* cOut = dir ? cb : cf;
  const int j = threadIdx.x;                  // 0..511

  __shared__ float h2[2][1024];               // [pp][k*2 + b]
  h2[0][j * 2] = 0.f;
  h2[0][j * 2 + 1] = 0.f;
  float c0 = 0.f, c1 = 0.f;
  __syncthreads();

  int p = 0;
  for (int t = 0; t < 128; ++t) {
    const int trow = dir ? (127 - t) : t;     // source position
    float4 z0 = *(const float4*)(xW + (size_t)(trow * 32 + b0) * 2048 + j * 4);
    float4 z1 = *(const float4*)(xW + (size_t)(trow * 32 + b0 + 1) * 2048 + j * 4);
    const float* hrow = h2[p];
#pragma unroll 8
    for (int k = 0; k < 512; ++k) {
      float4 u = Ux[k * 512 + j];
      float ha = hrow[k * 2], hb = hrow[k * 2 + 1];
      z0.x += ha * u.x; z0.y += ha * u.y; z0.z += ha * u.z; z0.w += ha * u.w;
      z1.x += hb * u.x; z1.y += hb * u.y; z1.z += hb * u.z; z1.w += hb * u.w;
    }
    c0 = sigm(z0.y) * c0 + sigm(z0.x) * tanhf(z0.z);
    float h0 = sigm(z0.w) * tanhf(c0);
    c1 = sigm(z1.y) * c1 + sigm(z1.x) * tanhf(z1.z);
    float h1 = sigm(z1.w) * tanhf(c1);
    h2[p ^ 1][j * 2] = h0;
    h2[p ^ 1][j * 2 + 1] = h1;
    hs[((size_t)trow * 32 + b0) * 512 + j] = h0;       // position-ordered
    hs[((size_t)trow * 32 + b0 + 1) * 512 + j] = h1;
    p ^= 1;
    __syncthreads();
  }
  cOut[(size_t)b0 * 512 + j] = c0;
  cOut[(size_t)(b0 + 1) * 512 + j] = c1;
}

// ---------------- fused decoder recurrence: 63 steps (attention deferred) ----------------
__global__ __launch_bounds__(512) void k_dec_fused(
    const float* __restrict__ yW, const float* __restrict__ Uxd,
    const float* __restrict__ prev_h, const float* __restrict__ prev_c,
    float* __restrict__ dec) {
  const int b = blockIdx.x;                   // 0..31
  const int j = threadIdx.x;                  // 0..511
  const float4* Ux = (const float4*)Uxd;

  __shared__ float h2[2][512];
  h2[0][j] = prev_h[(size_t)b * 512 + j];
  float c = prev_c[(size_t)b * 512 + j];
  __syncthreads();

  int p = 0;
  for (int t = 0; t < cTM1; ++t) {
    float4 z = *(const float4*)(yW + (size_t)(t * 32 + b) * 2048 + j * 4);
    const float* hrow = h2[p];
#pragma unroll 8
    for (int k = 0; k < 512; ++k) {
      float4 u = Ux[k * 512 + j];
      float h = hrow[k];
      z.x += h * u.x; z.y += h * u.y; z.z += h * u.z; z.w += h * u.w;
    }
    c = sigm(z.y) * c + sigm(z.x) * tanhf(z.z);
    float h = sigm(z.w) * tanhf(c);
    h2[p ^ 1][j] = h;
    dec[((size_t)b * cTM1 + t) * 1024 + 512 + j] = h;
    p ^= 1;
    __syncthreads();
  }
}

// ---------------- concat builder (bf16, zero-padded to 4224 rows) ----------------
__global__ __launch_bounds__(128) void k_cat_bf(const float* __restrict__ hs_f,
                                                const float* __restrict__ hs_b,
                                                const float* __restrict__ cf,
                                                const float* __restrict__ cb,
                                                __hip_bfloat16* __restrict__ cat) {
  int r = blockIdx.x;
  int tid = threadIdx.x;
  __hip_bfloat16* drow = cat + (size_t)r * 1024 + tid * 8;
  if (r >= 4160) {
#pragma unroll
    for (int i = 0; i < 8; ++i) drow[i] = __float2bfloat16(0.0f);
    return;
  }
  const float *pf, *pb;
  if (r < 4096) {
    int b = r >> 7, s = r & 127;
    pf = hs_f + ((size_t)s * 32 + b) * 512;
    pb = hs_b + ((size_t)s * 32 + b) * 512;
  } else if (r < 4128) {
    int b = r - 4096;
    pf = hs_f + ((size_t)127 * 32 + b) * 512;   // final fwd h
    pb = hs_b + ((size_t)b) * 512;              // final bwd h (position 0)
  } else {
    int b = r - 4128;
    pf = cf + (size_t)b * 512;
    pb = cb + (size_t)b * 512;
  }
  const float* s8 = (tid < 64) ? (pf + tid * 8) : (pb + (tid - 64) * 8);
#pragma unroll
  for (int i = 0; i < 8; ++i) drow[i] = __float2bfloat16(s8[i]);
}

// ---------------- batched attention over all (b,t) ----------------
__global__ __launch_bounds__(256) void k_attn_all(const float* __restrict__ src_h,
                                                  const float* __restrict__ neg,
                                                  float* __restrict__ dec) {
  int bid = blockIdx.x;               // 0..2015, XCD-localized by batch
  int xcd = bid & 7, idx = bid >> 3;  // idx 0..251
  int b = xcd + 8 * (idx / 63);
  int t = idx % 63;
  int tx = threadIdx.x;
  __shared__ float hv[cH];
  __shared__ float part[256];
  __shared__ float sc[cS];
  __shared__ float red[cS];
  float* drow = dec + ((size_t)b * cTM1 + t) * (2 * cH);
  hv[tx] = drow[cH + tx];
  hv[tx + 256] = drow[cH + tx + 256];
  __syncthreads();
  {
    int s = tx >> 1, half = tx & 1;
    const float4* sr = (const float4*)(src_h + ((size_t)b * cS + s) * cH + half * 256);
    const float4* hh = (const float4*)(hv + half * 256);
    float acc = 0.f;
#pragma unroll 8
    for (int k = 0; k < 64; ++k) {
      float4 v = sr[k], h4 = hh[k];
      acc += v.x * h4.x + v.y * h4.y + v.z * h4.z + v.w * h4.w;
    }
    part[tx] = acc;
  }
  __syncthreads();
  if (tx < cS) {
    float s0 = part[2 * tx] + part[2 * tx + 1] + neg[b * cS + tx];
    sc[tx] = s0;
    red[tx] = s0;
  }
  __syncthreads();
  for (int off = 64; off >= 1; off >>= 1) {
    if (tx < off) red[tx] = fmaxf(red[tx], red[tx + off]);
    __syncthreads();
  }
  float mx = red[0];
  __syncthreads();
  float e = 0.f;
  if (tx < cS) { e = expf(sc[tx] - mx); red[tx] = e; }
  __syncthreads();
  for (int off = 64; off >= 1; off >>= 1) {
    if (tx < off) red[tx] += red[tx + off];
    __syncthreads();
  }
  float inv = 1.0f / red[0];
  __syncthreads();
  if (tx < cS) sc[tx] = e * inv;
  __syncthreads();
  float a0 = 0.f, a1 = 0.f;
  for (int s = 0; s < cS; ++s) {
    float w = sc[s];
    const float* sr = src_h + ((size_t)b * cS + s) * cH;
    a0 += w * sr[tx];
    a1 += w * sr[tx + 256];
  }
  drow[tx] = a0;
  drow[tx + 256] = a1;
}

extern "C" void kernel_launch(void* const* d_in, const int* in_sizes, int n_in,
                              void* d_out, int out_size, void* d_ws, size_t ws_size,
                              hipStream_t stream) {
  const int* src = (const int*)d_in[0];
  const int* trg = (const int*)d_in[1];
  const float* E_src = (const float*)d_in[2];
  const float* E_trg = (const float*)d_in[3];
  const float* Wf = (const float*)d_in[4];
  const float* Uf = (const float*)d_in[5];
  const float* bf = (const float*)d_in[6];
  const float* Wb = (const float*)d_in[7];
  const float* Ub = (const float*)d_in[8];
  const float* bb = (const float*)d_in[9];
  const float* Wd = (const float*)d_in[10];
  const float* Ud = (const float*)d_in[11];
  const float* bd = (const float*)d_in[12];
  const float* fcW = (const float*)d_in[13];
  const float* fcb = (const float*)d_in[14];
  const float* clsW = (const float*)d_in[15];
  const float* clsb = (const float*)d_in[16];
  float* out = (float*)d_out;
  float* ws = (float*)d_ws;

  // ---- static layout (float offsets), total 36,737,024 floats = R2-proven size ----
  float* xWf = ws;                                  // 0        .. 8388608
  float* xWb = ws + 8388608;                        // 8388608  .. 16777216
  float* hs_f = ws + 16777216;                      // 2097152
  float* hs_b = ws + 18874368;                      // 2097152
  float* cf = ws + 20971520;                        // 16384
  float* cb = ws + 20987904;                        // 16384
  float* neg = ws + 21004288;                       // 4096
  float* fco = ws + 21008384;                       // 4160*512 = 2129920
  float* yW = ws + 23138304;                        // 2016*2048 = 4128768
  float* dec = ws + 27267072;                       // 32*63*1024 = 2064384
  float* Uxd = ws + 29331456;                       // 1048576
  float* pool = ws + 30380032;                      // 6356992 floats

  // pool / aliased transients
  float* xs = pool;                                 // 2097152
  float* ys = pool + 2097152;                       // 1032192
  float* Uxf = pool + 3145728;                      // 1048576
  float* Uxb = pool + 4194304;                      // 1048576
  __hip_bfloat16* xs_bf = (__hip_bfloat16*)hs_f;    // 4096x512 (dead before enc writes)
  __hip_bfloat16* ys_bf = (__hip_bfloat16*)hs_b;    // 2048x512
  __hip_bfloat16* Wtfx = (__hip_bfloat16*)fco;                 // 2048x512
  __hip_bfloat16* Wtbx = (__hip_bfloat16*)(fco + 524288);      // 2048x512
  __hip_bfloat16* Wtdx = (__hip_bfloat16*)(fco + 1048576);     // 2048x512
  float* bfx = fco + 1572864;                       // 2048
  float* bbx = fco + 1574912;                       // 2048
  float* bdx = fco + 1576960;                       // 2048
  __hip_bfloat16* cat_bf = (__hip_bfloat16*)pool;              // 4224x1024
  __hip_bfloat16* fcWt = (__hip_bfloat16*)(pool + 2162688);    // 512x1024
  __hip_bfloat16* clsWt = (__hip_bfloat16*)xWf;                // 32000x1024 (spans xWf+xWb)
  __hip_bfloat16* dec_bf = (__hip_bfloat16*)pool;              // 2048x1024

  // phase A: embeddings, conversions, weight prep
  k_embed_src<<<4096, 128, 0, stream>>>(src, E_src, xs, neg);
  k_embed_trg<<<2016, 128, 0, stream>>>(trg, E_trg, ys);
  k_f2b<<<8192, 256, 0, stream>>>(xs, xs_bf, 4096 * 512, 4096 * 512);
  k_f2b<<<4096, 256, 0, stream>>>(ys, ys_bf, 2016 * 512, 2048 * 512);
  k_f2bT<<<dim3(64, 16), 256, 0, stream>>>(Wf, Wtfx, 512, 2048, 1);
  k_f2bT<<<dim3(64, 16), 256, 0, stream>>>(Wb, Wtbx, 512, 2048, 1);
  k_f2bT<<<dim3(64, 16), 256, 0, stream>>>(Wd, Wtdx, 512, 2048, 1);
  k_permb<<<8, 256, 0, stream>>>(bf, bfx);
  k_permb<<<8, 256, 0, stream>>>(bb, bbx);
  k_permb<<<8, 256, 0, stream>>>(bd, bdx);
  k_prepU<<<1024, 256, 0, stream>>>(Uf, Uxf);
  k_prepU<<<1024, 256, 0, stream>>>(Ub, Uxb);
  k_prepU<<<1024, 256, 0, stream>>>(Ud, Uxd);

  // input projections (gate-interleaved columns)
  k_bgemm<<<dim3(32, 16), 256, 0, stream>>>(xs_bf, Wtfx, bfx, xWf, 4096, 512, 2048);
  k_bgemm<<<dim3(32, 16), 256, 0, stream>>>(xs_bf, Wtbx, bbx, xWb, 4096, 512, 2048);
  k_bgemm<<<dim3(16, 16), 256, 0, stream>>>(ys_bf, Wtdx, bdx, yW, 2016, 512, 2048);

  // phase B: fused encoder (128 steps, both dirs)
  k_enc_fused<<<32, 512, 0, stream>>>(xWf, xWb, Uxf, Uxb, hs_f, hs_b, cf, cb);

  // phase C: concat + fc projection (bf16 MFMA)
  k_cat_bf<<<4224, 128, 0, stream>>>(hs_f, hs_b, cf, cb, cat_bf);
  k_f2bT<<<dim3(16, 32), 256, 0, stream>>>(fcW, fcWt, 1024, 512, 0);
  k_bgemm<<<dim3(33, 4), 256, 0, stream>>>(cat_bf, fcWt, fcb, fco, 4160, 1024, 512);

  // classifier weight convert (xWf/xWb dead after encoder)
  k_f2bT<<<dim3(1000, 32), 256, 0, stream>>>(clsW, clsWt, 1024, 32000, 0);

  // phase D: fused decoder recurrence, then batched attention
  const float* prev_h = fco + (size_t)4096 * 512;
  const float* prev_c = fco + (size_t)4128 * 512;
  k_dec_fused<<<32, 512, 0, stream>>>(yW, Uxd, prev_h, prev_c, dec);
  k_attn_all<<<2016, 256, 0, stream>>>(fco, neg, dec);

  // phase F: classifier
  k_f2b<<<8192, 256, 0, stream>>>(dec, dec_bf, 2016 * 1024, 2048 * 1024);
  k_bgemm<<<dim3(16, 250), 256, 0, stream>>>(dec_bf, clsWt, clsb, out, 2016, 1024, 32000);
}

// Round 4
// 4880.031 us; speedup vs baseline: 1.9029x; 1.4421x over previous
//
#include <hip/hip_runtime.h>
#include <hip/hip_bf16.h>
#include <stdint.h>

constexpr int cB = 32, cS = 128, cT = 64, cH = 512, cH4 = 2048, cVT = 32000, cTM1 = 63;

typedef __attribute__((ext_vector_type(8))) __bf16 bf16x8;
typedef __attribute__((ext_vector_type(4))) float f32x4;

__device__ __forceinline__ float sigm(float x) { return 1.0f / (1.0f + expf(-x)); }

// ---------------- device-scope grid barrier (persistent kernels) ----------------
// ctr/flag in global ws, zeroed by k_init_bars each launch. Monotonic gen.
__device__ __forceinline__ void gridbar(unsigned* ctr, unsigned* flag,
                                        unsigned nblk, unsigned gen) {
  __syncthreads();
  if (threadIdx.x == 0) {
    __threadfence();   // release: drain + wbl2 (cross-XCD visibility of h stores)
    unsigned old = __hip_atomic_fetch_add(ctr, 1u, __ATOMIC_RELAXED,
                                          __HIP_MEMORY_SCOPE_AGENT);
    if (old == gen * nblk - 1u) {
      __hip_atomic_store(flag, gen, __ATOMIC_RELAXED, __HIP_MEMORY_SCOPE_AGENT);
    } else {
      while (__hip_atomic_load(flag, __ATOMIC_RELAXED, __HIP_MEMORY_SCOPE_AGENT) < gen)
        __builtin_amdgcn_s_sleep(2);
    }
    __threadfence();   // acquire: invalidate L1/L2 before re-reading h
  }
  __syncthreads();
}

__global__ __launch_bounds__(64) void k_init_bars(unsigned* p) {
  if (threadIdx.x < 16) p[threadIdx.x] = 0u;
}

// ---------------- embeddings ----------------
__global__ __launch_bounds__(128) void k_embed_src(const int* __restrict__ src,
                                                   const float* __restrict__ E,
                                                   float* __restrict__ xs,
                                                   float* __restrict__ neg) {
  int sb = blockIdx.x;            // s*B + b
  int s = sb >> 5, b = sb & 31;
  int tok = src[b * cS + s];
  const float4* erow = (const float4*)(E + (size_t)tok * cH);
  float4* xrow = (float4*)(xs + (size_t)sb * cH);
  xrow[threadIdx.x] = erow[threadIdx.x];
  if (threadIdx.x == 0) neg[b * cS + s] = (tok == 0) ? -1e9f : 0.0f;
}

__global__ __launch_bounds__(128) void k_embed_trg(const int* __restrict__ trg,
                                                   const float* __restrict__ E,
                                                   float* __restrict__ ys) {
  int tb = blockIdx.x;            // t*B + b, t < 63
  int t = tb >> 5, b = tb & 31;
  int tok = trg[b * cT + t];
  const float4* erow = (const float4*)(E + (size_t)tok * cH);
  float4* yrow = (float4*)(ys + (size_t)tb * cH);
  yrow[threadIdx.x] = erow[threadIdx.x];
}

// ---------------- fp32 -> bf16 elementwise with zero tail-pad ----------------
__global__ __launch_bounds__(256) void k_f2b(const float* __restrict__ src,
                                             __hip_bfloat16* __restrict__ dst,
                                             int srcN, int dstN) {
  int i = blockIdx.x * 256 + threadIdx.x;
  if (i < dstN) {
    float v = (i < srcN) ? src[i] : 0.0f;
    dst[i] = __float2bfloat16(v);
  }
}

// ---------------- fp32 [K][N] -> bf16 [N][K] transpose-convert ----------------
// gi=1: permute output row n -> (n&511)*4 + (n>>9)  (gate interleave)
__global__ __launch_bounds__(256) void k_f2bT(const float* __restrict__ src,
                                              __hip_bfloat16* __restrict__ dst,
                                              int K, int N, int gi) {
  __shared__ float t[32][33];
  int nt = blockIdx.x * 32, kt = blockIdx.y * 32;
  int c = threadIdx.x & 31, r0 = threadIdx.x >> 5;
#pragma unroll
  for (int i = 0; i < 4; ++i) {
    int r = r0 + i * 8;
    t[r][c] = src[(size_t)(kt + r) * N + nt + c];
  }
  __syncthreads();
#pragma unroll
  for (int i = 0; i < 4; ++i) {
    int row = nt + r0 + i * 8;
    int pr = gi ? (((row & 511) << 2) | (row >> 9)) : row;
    dst[(size_t)pr * K + kt + c] = __float2bfloat16(t[c][r0 + i * 8]);
  }
}

// ---------------- bias gate-interleave: out[j*4+g] = in[g*512+j] ----------------
__global__ __launch_bounds__(256) void k_permb(const float* __restrict__ in,
                                               float* __restrict__ out) {
  int i = blockIdx.x * 256 + threadIdx.x;   // 0..2047
  out[i] = in[(i & 3) * 512 + (i >> 2)];
}

// ---------------- U[512][2048] -> Ux[k][j][4] fp32 gate-interleaved ----------------
__global__ __launch_bounds__(256) void k_prepU(const float* __restrict__ U,
                                               float* __restrict__ Ux) {
  int idx = blockIdx.x * 256 + threadIdx.x;   // 0..262143
  int k = idx >> 9, j = idx & 511;
  float4 v;
  v.x = U[(size_t)k * 2048 + j];
  v.y = U[(size_t)k * 2048 + 512 + j];
  v.z = U[(size_t)k * 2048 + 1024 + j];
  v.w = U[(size_t)k * 2048 + 1536 + j];
  ((float4*)Ux)[idx] = v;
}

// ---------------- bf16 MFMA GEMM: C[M,N] = A[M,K] @ Bt[N,K]^T + bias ----------------
__global__ __launch_bounds__(256) void k_bgemm(const __hip_bfloat16* __restrict__ A,
                                               const __hip_bfloat16* __restrict__ Bt,
                                               const float* __restrict__ bias,
                                               float* __restrict__ C,
                                               int M, int K, int N) {
  __shared__ __hip_bfloat16 As[128 * 64];
  __shared__ __hip_bfloat16 Bs[128 * 64];
  const int tid = threadIdx.x;
  const int lane = tid & 63;
  const int wave = tid >> 6;
  const int wr = wave >> 1, wc = wave & 1;
  const int bm = blockIdx.x * 128, bn = blockIdx.y * 128;

  f32x4 acc[4][4] = {};

  const int srow = lane >> 3;
  const int scol = (lane & 7) * 8;

  for (int kt = 0; kt < K; kt += 64) {
#pragma unroll
    for (int i = 0; i < 4; ++i) {
      int c = wave * 4 + i;
      const __hip_bfloat16* ga = A + (size_t)(bm + c * 8 + srow) * K + kt + scol;
      __builtin_amdgcn_global_load_lds(
          (const __attribute__((address_space(1))) uint32_t*)ga,
          (__attribute__((address_space(3))) uint32_t*)(As + c * 512), 16, 0, 0);
      const __hip_bfloat16* gb = Bt + (size_t)(bn + c * 8 + srow) * K + kt + scol;
      __builtin_amdgcn_global_load_lds(
          (const __attribute__((address_space(1))) uint32_t*)gb,
          (__attribute__((address_space(3))) uint32_t*)(Bs + c * 512), 16, 0, 0);
    }
    __syncthreads();

#pragma unroll
    for (int kk = 0; kk < 64; kk += 32) {
      const int ko = kk + (lane >> 4) * 8;
      bf16x8 a[4], b[4];
      const int ar = wr * 64 + (lane & 15);
#pragma unroll
      for (int m = 0; m < 4; ++m)
        a[m] = *(const bf16x8*)(As + (size_t)(ar + m * 16) * 64 + ko);
      const int br = wc * 64 + (lane & 15);
#pragma unroll
      for (int n = 0; n < 4; ++n)
        b[n] = *(const bf16x8*)(Bs + (size_t)(br + n * 16) * 64 + ko);
#pragma unroll
      for (int m = 0; m < 4; ++m)
#pragma unroll
        for (int n = 0; n < 4; ++n)
          acc[m][n] = __builtin_amdgcn_mfma_f32_16x16x32_bf16(a[m], b[n], acc[m][n], 0, 0, 0);
    }
    __syncthreads();
  }

#pragma unroll
  for (int m = 0; m < 4; ++m) {
    const int row0 = bm + wr * 64 + m * 16 + (lane >> 4) * 4;
#pragma unroll
    for (int n = 0; n < 4; ++n) {
      const int col = bn + wc * 64 + n * 16 + (lane & 15);
      const float bv = bias[col];
#pragma unroll
      for (int r = 0; r < 4; ++r) {
        const int row = row0 + r;
        if (row < M) C[(size_t)row * N + col] = acc[m][n][r] + bv;
      }
    }
  }
}

// ---------------- persistent encoder: 128 blocks (dir = bid>>6, jg = bid&63) ----------------
// thread: b = tid>>3, jo = tid&7, j = jg*8+jo. c in registers, h via global hs + LDS stage.
__global__ __launch_bounds__(256) void k_enc_coop(
    const float* __restrict__ xWf, const float* __restrict__ xWb,
    const float* __restrict__ Uxf, const float* __restrict__ Uxb,
    float* __restrict__ hs_f, float* __restrict__ hs_b,
    float* __restrict__ cf, float* __restrict__ cb,
    unsigned* ctr, unsigned* flag) {
  const int bid = blockIdx.x;
  const int dir = bid >> 6;
  const int jg = bid & 63;
  const float* xW = dir ? xWb : xWf;
  const float4* Ux = (const float4*)(dir ? Uxb : Uxf);
  float* hs = dir ? hs_b : hs_f;
  float* cOut = dir ? cb : cf;
  const int tid = threadIdx.x;
  const int b = tid >> 3, jo = tid & 7;
  const int j = jg * 8 + jo;

  __shared__ float hl[512 * 33];   // [k][b], pad 33 for conflict-free access
  float c = 0.0f;

  for (int t = 0; t < 128; ++t) {
    if (t == 0) {
      for (int i = tid; i < 4096; i += 256) {
        int idx = i * 4;
        int jj = idx & 511, bb = idx >> 9;
        hl[(jj + 0) * 33 + bb] = 0.f;
        hl[(jj + 1) * 33 + bb] = 0.f;
        hl[(jj + 2) * 33 + bb] = 0.f;
        hl[(jj + 3) * 33 + bb] = 0.f;
      }
    } else {
      const int prow = dir ? (128 - t) : (t - 1);
      const float4* src4 = (const float4*)(hs + (size_t)prow * 32 * 512);
#pragma unroll
      for (int i = 0; i < 16; ++i) {
        int i4 = tid + i * 256;
        float4 v = src4[i4];
        int idx = i4 * 4;
        int jj = idx & 511, bb = idx >> 9;
        hl[(jj + 0) * 33 + bb] = v.x;
        hl[(jj + 1) * 33 + bb] = v.y;
        hl[(jj + 2) * 33 + bb] = v.z;
        hl[(jj + 3) * 33 + bb] = v.w;
      }
    }
    __syncthreads();

    const int trow = dir ? (127 - t) : t;
    float4 z = *(const float4*)(xW + ((size_t)(trow * 32 + b)) * 2048 + j * 4);
#pragma unroll 8
    for (int k = 0; k < 512; ++k) {
      float4 u = Ux[k * 512 + j];
      float h = hl[k * 33 + b];
      z.x += h * u.x; z.y += h * u.y; z.z += h * u.z; z.w += h * u.w;
    }
    c = sigm(z.y) * c + sigm(z.x) * tanhf(z.z);
    float h = sigm(z.w) * tanhf(c);
    hs[((size_t)trow * 32 + b) * 512 + j] = h;

    if (t < 127) gridbar(ctr, flag, 128u, (unsigned)(t + 1));
  }
  cOut[(size_t)b * 512 + j] = c;
}

// ---------------- persistent decoder recurrence: 64 blocks ----------------
// hdec double-buffered [2][32][512] to avoid cross-block WAR on h state.
__global__ __launch_bounds__(256) void k_dec_coop(
    const float* __restrict__ yW, const float* __restrict__ Uxd,
    const float* __restrict__ prev_h, const float* __restrict__ prev_c,
    float* __restrict__ hdec, float* __restrict__ dec,
    unsigned* ctr, unsigned* flag) {
  const int jg = blockIdx.x;     // 0..63
  const float4* Ux = (const float4*)Uxd;
  const int tid = threadIdx.x;
  const int b = tid >> 3, jo = tid & 7;
  const int j = jg * 8 + jo;

  __shared__ float hl[512 * 33];
  float c = prev_c[(size_t)b * 512 + j];

  for (int t = 0; t < cTM1; ++t) {
    const float4* src4 = (const float4*)(t == 0 ? prev_h
                                                : hdec + (size_t)((t - 1) & 1) * 16384);
#pragma unroll
    for (int i = 0; i < 16; ++i) {
      int i4 = tid + i * 256;
      float4 v = src4[i4];
      int idx = i4 * 4;
      int jj = idx & 511, bb = idx >> 9;
      hl[(jj + 0) * 33 + bb] = v.x;
      hl[(jj + 1) * 33 + bb] = v.y;
      hl[(jj + 2) * 33 + bb] = v.z;
      hl[(jj + 3) * 33 + bb] = v.w;
    }
    __syncthreads();

    float4 z = *(const float4*)(yW + ((size_t)(t * 32 + b)) * 2048 + j * 4);
#pragma unroll 8
    for (int k = 0; k < 512; ++k) {
      float4 u = Ux[k * 512 + j];
      float h = hl[k * 33 + b];
      z.x += h * u.x; z.y += h * u.y; z.z += h * u.z; z.w += h * u.w;
    }
    c = sigm(z.y) * c + sigm(z.x) * tanhf(z.z);
    float h = sigm(z.w) * tanhf(c);
    hdec[(size_t)(t & 1) * 16384 + (size_t)b * 512 + j] = h;
    dec[((size_t)b * cTM1 + t) * 1024 + 512 + j] = h;

    if (t < cTM1 - 1) gridbar(ctr, flag, 64u, (unsigned)(t + 1));
  }
}

// ---------------- concat builder (bf16, zero-padded to 4224 rows) ----------------
__global__ __launch_bounds__(128) void k_cat_bf(const float* __restrict__ hs_f,
                                                const float* __restrict__ hs_b,
                                                const float* __restrict__ cf,
                                                const float* __restrict__ cb,
                                                __hip_bfloat16* __restrict__ cat) {
  int r = blockIdx.x;
  int tid = threadIdx.x;
  __hip_bfloat16* drow = cat + (size_t)r * 1024 + tid * 8;
  if (r >= 4160) {
#pragma unroll
    for (int i = 0; i < 8; ++i) drow[i] = __float2bfloat16(0.0f);
    return;
  }
  const float *pf, *pb;
  if (r < 4096) {
    int b = r >> 7, s = r & 127;
    pf = hs_f + ((size_t)s * 32 + b) * 512;
    pb = hs_b + ((size_t)s * 32 + b) * 512;
  } else if (r < 4128) {
    int b = r - 4096;
    pf = hs_f + ((size_t)127 * 32 + b) * 512;   // final fwd h
    pb = hs_b + ((size_t)b) * 512;              // final bwd h (position 0)
  } else {
    int b = r - 4128;
    pf = cf + (size_t)b * 512;
    pb = cb + (size_t)b * 512;
  }
  const float* s8 = (tid < 64) ? (pf + tid * 8) : (pb + (tid - 64) * 8);
#pragma unroll
  for (int i = 0; i < 8; ++i) drow[i] = __float2bfloat16(s8[i]);
}

// ---------------- batched attention over all (b,t) ----------------
__global__ __launch_bounds__(256) void k_attn_all(const float* __restrict__ src_h,
                                                  const float* __restrict__ neg,
                                                  float* __restrict__ dec) {
  int bid = blockIdx.x;               // 0..2015, XCD-localized by batch
  int xcd = bid & 7, idx = bid >> 3;  // idx 0..251
  int b = xcd + 8 * (idx / 63);
  int t = idx % 63;
  int tx = threadIdx.x;
  __shared__ float hv[cH];
  __shared__ float part[256];
  __shared__ float sc[cS];
  __shared__ float red[cS];
  float* drow = dec + ((size_t)b * cTM1 + t) * (2 * cH);
  hv[tx] = drow[cH + tx];
  hv[tx + 256] = drow[cH + tx + 256];
  __syncthreads();
  {
    int s = tx >> 1, half = tx & 1;
    const float4* sr = (const float4*)(src_h + ((size_t)b * cS + s) * cH + half * 256);
    const float4* hh = (const float4*)(hv + half * 256);
    float acc = 0.f;
#pragma unroll 8
    for (int k = 0; k < 64; ++k) {
      float4 v = sr[k], h4 = hh[k];
      acc += v.x * h4.x + v.y * h4.y + v.z * h4.z + v.w * h4.w;
    }
    part[tx] = acc;
  }
  __syncthreads();
  if (tx < cS) {
    float s0 = part[2 * tx] + part[2 * tx + 1] + neg[b * cS + tx];
    sc[tx] = s0;
    red[tx] = s0;
  }
  __syncthreads();
  for (int off = 64; off >= 1; off >>= 1) {
    if (tx < off) red[tx] = fmaxf(red[tx], red[tx + off]);
    __syncthreads();
  }
  float mx = red[0];
  __syncthreads();
  float e = 0.f;
  if (tx < cS) { e = expf(sc[tx] - mx); red[tx] = e; }
  __syncthreads();
  for (int off = 64; off >= 1; off >>= 1) {
    if (tx < off) red[tx] += red[tx + off];
    __syncthreads();
  }
  float inv = 1.0f / red[0];
  __syncthreads();
  if (tx < cS) sc[tx] = e * inv;
  __syncthreads();
  float a0 = 0.f, a1 = 0.f;
  for (int s = 0; s < cS; ++s) {
    float w = sc[s];
    const float* sr = src_h + ((size_t)b * cS + s) * cH;
    a0 += w * sr[tx];
    a1 += w * sr[tx + 256];
  }
  drow[tx] = a0;
  drow[tx + 256] = a1;
}

extern "C" void kernel_launch(void* const* d_in, const int* in_sizes, int n_in,
                              void* d_out, int out_size, void* d_ws, size_t ws_size,
                              hipStream_t stream) {
  const int* src = (const int*)d_in[0];
  const int* trg = (const int*)d_in[1];
  const float* E_src = (const float*)d_in[2];
  const float* E_trg = (const float*)d_in[3];
  const float* Wf = (const float*)d_in[4];
  const float* Uf = (const float*)d_in[5];
  const float* bf = (const float*)d_in[6];
  const float* Wb = (const float*)d_in[7];
  const float* Ub = (const float*)d_in[8];
  const float* bb = (const float*)d_in[9];
  const float* Wd = (const float*)d_in[10];
  const float* Ud = (const float*)d_in[11];
  const float* bd = (const float*)d_in[12];
  const float* fcW = (const float*)d_in[13];
  const float* fcb = (const float*)d_in[14];
  const float* clsW = (const float*)d_in[15];
  const float* clsb = (const float*)d_in[16];
  float* out = (float*)d_out;
  float* ws = (float*)d_ws;

  // ---- static layout (float offsets), total 36,737,024 floats = R3-proven size ----
  float* xWf = ws;                                  // 8388608
  float* xWb = ws + 8388608;                        // 8388608
  float* hs_f = ws + 16777216;                      // 2097152
  float* hs_b = ws + 18874368;                      // 2097152
  float* cf = ws + 20971520;                        // 16384
  float* cb = ws + 20987904;                        // 16384
  float* neg = ws + 21004288;                       // 4096
  float* fco = ws + 21008384;                       // 2129920
  float* yW = ws + 23138304;                        // 4128768
  float* dec = ws + 27267072;                       // 2064384
  float* Uxd = ws + 29331456;                       // 1048576
  float* pool = ws + 30380032;                      // 6356992

  // pool transients
  float* xs = pool;                                 // 2097152 (dead after f2b)
  float* ys = pool + 2097152;                       // 1032192 (dead after f2b)
  float* Uxf = pool + 3145728;                      // 1048576 (live during enc)
  float* Uxb = pool + 4194304;                      // 1048576 (live during enc)
  __hip_bfloat16* xs_bf = (__hip_bfloat16*)hs_f;    // dead before enc writes
  __hip_bfloat16* ys_bf = (__hip_bfloat16*)hs_b;
  __hip_bfloat16* Wtfx = (__hip_bfloat16*)fco;
  __hip_bfloat16* Wtbx = (__hip_bfloat16*)(fco + 524288);
  __hip_bfloat16* Wtdx = (__hip_bfloat16*)(fco + 1048576);
  float* bfx = fco + 1572864;
  float* bbx = fco + 1574912;
  float* bdx = fco + 1576960;
  __hip_bfloat16* cat_bf = (__hip_bfloat16*)pool;              // 4224x1024 -> pool..2162688
  __hip_bfloat16* fcWt = (__hip_bfloat16*)(pool + 2162688);    // ..2424832
  __hip_bfloat16* clsWt = (__hip_bfloat16*)xWf;                // 32000x1024
  __hip_bfloat16* dec_bf = (__hip_bfloat16*)pool;              // 2048x1024
  // barrier + decoder-h zone: gap 2424832..3129344 (ys dead by then)
  unsigned* bars = (unsigned*)(pool + 2500000);     // 16 uints
  float* hdec = pool + 2500016;                     // 2x16384

  // phase A: embeddings, conversions, weight prep
  k_embed_src<<<4096, 128, 0, stream>>>(src, E_src, xs, neg);
  k_embed_trg<<<2016, 128, 0, stream>>>(trg, E_trg, ys);
  k_f2b<<<8192, 256, 0, stream>>>(xs, xs_bf, 4096 * 512, 4096 * 512);
  k_f2b<<<4096, 256, 0, stream>>>(ys, ys_bf, 2016 * 512, 2048 * 512);
  k_f2bT<<<dim3(64, 16), 256, 0, stream>>>(Wf, Wtfx, 512, 2048, 1);
  k_f2bT<<<dim3(64, 16), 256, 0, stream>>>(Wb, Wtbx, 512, 2048, 1);
  k_f2bT<<<dim3(64, 16), 256, 0, stream>>>(Wd, Wtdx, 512, 2048, 1);
  k_permb<<<8, 256, 0, stream>>>(bf, bfx);
  k_permb<<<8, 256, 0, stream>>>(bb, bbx);
  k_permb<<<8, 256, 0, stream>>>(bd, bdx);
  k_prepU<<<1024, 256, 0, stream>>>(Uf, Uxf);
  k_prepU<<<1024, 256, 0, stream>>>(Ub, Uxb);
  k_prepU<<<1024, 256, 0, stream>>>(Ud, Uxd);

  // input projections (gate-interleaved columns)
  k_bgemm<<<dim3(32, 16), 256, 0, stream>>>(xs_bf, Wtfx, bfx, xWf, 4096, 512, 2048);
  k_bgemm<<<dim3(32, 16), 256, 0, stream>>>(xs_bf, Wtbx, bbx, xWb, 4096, 512, 2048);
  k_bgemm<<<dim3(16, 16), 256, 0, stream>>>(ys_bf, Wtdx, bdx, yW, 2016, 512, 2048);

  // phase B: persistent encoder (whole chip per step, grid barrier)
  k_init_bars<<<1, 64, 0, stream>>>(bars);
  k_enc_coop<<<128, 256, 0, stream>>>(xWf, xWb, Uxf, Uxb, hs_f, hs_b, cf, cb,
                                      bars + 0, bars + 1);

  // phase C: concat + fc projection (bf16 MFMA)
  k_cat_bf<<<4224, 128, 0, stream>>>(hs_f, hs_b, cf, cb, cat_bf);
  k_f2bT<<<dim3(16, 32), 256, 0, stream>>>(fcW, fcWt, 1024, 512, 0);
  k_bgemm<<<dim3(33, 4), 256, 0, stream>>>(cat_bf, fcWt, fcb, fco, 4160, 1024, 512);

  // classifier weight convert (xWf/xWb dead after encoder)
  k_f2bT<<<dim3(1000, 32), 256, 0, stream>>>(clsW, clsWt, 1024, 32000, 0);

  // phase D: persistent decoder recurrence, then batched attention
  const float* prev_h = fco + (size_t)4096 * 512;
  const float* prev_c = fco + (size_t)4128 * 512;
  k_dec_coop<<<64, 256, 0, stream>>>(yW, Uxd, prev_h, prev_c, hdec, dec,
                                     bars + 2, bars + 3);
  k_attn_all<<<2016, 256, 0, stream>>>(fco, neg, dec);

  // phase F: classifier
  k_f2b<<<8192, 256, 0, stream>>>(dec, dec_bf, 2016 * 1024, 2048 * 1024);
  k_bgemm<<<dim3(16, 250), 256, 0, stream>>>(dec_bf, clsWt, clsb, out, 2016, 1024, 32000);
}

// Round 5
// 1773.716 us; speedup vs baseline: 5.2354x; 2.7513x over previous
//
#include <hip/hip_runtime.h>
#include <hip/hip_bf16.h>
#include <stdint.h>

constexpr int cB = 32, cS = 128, cT = 64, cH = 512, cH4 = 2048, cVT = 32000, cTM1 = 63;

typedef __attribute__((ext_vector_type(8))) __bf16 bf16x8;
typedef __attribute__((ext_vector_type(4))) float f32x4;

__device__ __forceinline__ float sigm(float x) { return 1.0f / (1.0f + expf(-x)); }

// ---------------- device-scope grid barrier (persistent kernels, R4-proven) ----------------
__device__ __forceinline__ void gridbar(unsigned* ctr, unsigned* flag,
                                        unsigned nblk, unsigned gen) {
  __syncthreads();
  if (threadIdx.x == 0) {
    __threadfence();   // release
    unsigned old = __hip_atomic_fetch_add(ctr, 1u, __ATOMIC_RELAXED,
                                          __HIP_MEMORY_SCOPE_AGENT);
    if (old == gen * nblk - 1u) {
      __hip_atomic_store(flag, gen, __ATOMIC_RELAXED, __HIP_MEMORY_SCOPE_AGENT);
    } else {
      while (__hip_atomic_load(flag, __ATOMIC_RELAXED, __HIP_MEMORY_SCOPE_AGENT) < gen)
        __builtin_amdgcn_s_sleep(2);
    }
    __threadfence();   // acquire
  }
  __syncthreads();
}

__global__ __launch_bounds__(64) void k_init_bars(unsigned* p) {
  if (threadIdx.x < 16) p[threadIdx.x] = 0u;
}

// ---------------- embeddings ----------------
__global__ __launch_bounds__(128) void k_embed_src(const int* __restrict__ src,
                                                   const float* __restrict__ E,
                                                   float* __restrict__ xs,
                                                   float* __restrict__ neg) {
  int sb = blockIdx.x;            // s*B + b
  int s = sb >> 5, b = sb & 31;
  int tok = src[b * cS + s];
  const float4* erow = (const float4*)(E + (size_t)tok * cH);
  float4* xrow = (float4*)(xs + (size_t)sb * cH);
  xrow[threadIdx.x] = erow[threadIdx.x];
  if (threadIdx.x == 0) neg[b * cS + s] = (tok == 0) ? -1e9f : 0.0f;
}

__global__ __launch_bounds__(128) void k_embed_trg(const int* __restrict__ trg,
                                                   const float* __restrict__ E,
                                                   float* __restrict__ ys) {
  int tb = blockIdx.x;            // t*B + b, t < 63
  int t = tb >> 5, b = tb & 31;
  int tok = trg[b * cT + t];
  const float4* erow = (const float4*)(E + (size_t)tok * cH);
  float4* yrow = (float4*)(ys + (size_t)tb * cH);
  yrow[threadIdx.x] = erow[threadIdx.x];
}

// ---------------- fp32 -> bf16 elementwise with zero tail-pad ----------------
__global__ __launch_bounds__(256) void k_f2b(const float* __restrict__ src,
                                             __hip_bfloat16* __restrict__ dst,
                                             int srcN, int dstN) {
  int i = blockIdx.x * 256 + threadIdx.x;
  if (i < dstN) {
    float v = (i < srcN) ? src[i] : 0.0f;
    dst[i] = __float2bfloat16(v);
  }
}

// ---------------- fp32 [K][N] -> bf16 [N][K] transpose-convert ----------------
// gi=1: permute output row n -> (n&511)*4 + (n>>9)  (gate interleave)
__global__ __launch_bounds__(256) void k_f2bT(const float* __restrict__ src,
                                              __hip_bfloat16* __restrict__ dst,
                                              int K, int N, int gi) {
  __shared__ float t[32][33];
  int nt = blockIdx.x * 32, kt = blockIdx.y * 32;
  int c = threadIdx.x & 31, r0 = threadIdx.x >> 5;
#pragma unroll
  for (int i = 0; i < 4; ++i) {
    int r = r0 + i * 8;
    t[r][c] = src[(size_t)(kt + r) * N + nt + c];
  }
  __syncthreads();
#pragma unroll
  for (int i = 0; i < 4; ++i) {
    int row = nt + r0 + i * 8;
    int pr = gi ? (((row & 511) << 2) | (row >> 9)) : row;
    dst[(size_t)pr * K + kt + c] = __float2bfloat16(t[c][r0 + i * 8]);
  }
}

// ---------------- bias gate-interleave: out[j*4+g] = in[g*512+j] ----------------
__global__ __launch_bounds__(256) void k_permb(const float* __restrict__ in,
                                               float* __restrict__ out) {
  int i = blockIdx.x * 256 + threadIdx.x;   // 0..2047
  out[i] = in[(i & 3) * 512 + (i >> 2)];
}

// ---------------- bf16 MFMA GEMM: C[M,N] = A[M,K] @ Bt[N,K]^T + bias ----------------
__global__ __launch_bounds__(256) void k_bgemm(const __hip_bfloat16* __restrict__ A,
                                               const __hip_bfloat16* __restrict__ Bt,
                                               const float* __restrict__ bias,
                                               float* __restrict__ C,
                                               int M, int K, int N) {
  __shared__ __hip_bfloat16 As[128 * 64];
  __shared__ __hip_bfloat16 Bs[128 * 64];
  const int tid = threadIdx.x;
  const int lane = tid & 63;
  const int wave = tid >> 6;
  const int wr = wave >> 1, wc = wave & 1;
  const int bm = blockIdx.x * 128, bn = blockIdx.y * 128;

  f32x4 acc[4][4] = {};

  const int srow = lane >> 3;
  const int scol = (lane & 7) * 8;

  for (int kt = 0; kt < K; kt += 64) {
#pragma unroll
    for (int i = 0; i < 4; ++i) {
      int c = wave * 4 + i;
      const __hip_bfloat16* ga = A + (size_t)(bm + c * 8 + srow) * K + kt + scol;
      __builtin_amdgcn_global_load_lds(
          (const __attribute__((address_space(1))) uint32_t*)ga,
          (__attribute__((address_space(3))) uint32_t*)(As + c * 512), 16, 0, 0);
      const __hip_bfloat16* gb = Bt + (size_t)(bn + c * 8 + srow) * K + kt + scol;
      __builtin_amdgcn_global_load_lds(
          (const __attribute__((address_space(1))) uint32_t*)gb,
          (__attribute__((address_space(3))) uint32_t*)(Bs + c * 512), 16, 0, 0);
    }
    __syncthreads();

#pragma unroll
    for (int kk = 0; kk < 64; kk += 32) {
      const int ko = kk + (lane >> 4) * 8;
      bf16x8 a[4], b[4];
      const int ar = wr * 64 + (lane & 15);
#pragma unroll
      for (int m = 0; m < 4; ++m)
        a[m] = *(const bf16x8*)(As + (size_t)(ar + m * 16) * 64 + ko);
      const int br = wc * 64 + (lane & 15);
#pragma unroll
      for (int n = 0; n < 4; ++n)
        b[n] = *(const bf16x8*)(Bs + (size_t)(br + n * 16) * 64 + ko);
#pragma unroll
      for (int m = 0; m < 4; ++m)
#pragma unroll
        for (int n = 0; n < 4; ++n)
          acc[m][n] = __builtin_amdgcn_mfma_f32_16x16x32_bf16(a[m], b[n], acc[m][n], 0, 0, 0);
    }
    __syncthreads();
  }

#pragma unroll
  for (int m = 0; m < 4; ++m) {
    const int row0 = bm + wr * 64 + m * 16 + (lane >> 4) * 4;
#pragma unroll
    for (int n = 0; n < 4; ++n) {
      const int col = bn + wc * 64 + n * 16 + (lane & 15);
      const float bv = bias[col];
#pragma unroll
      for (int r = 0; r < 4; ++r) {
        const int row = row0 + r;
        if (row < M) C[(size_t)row * N + col] = acc[m][n][r] + bv;
      }
    }
  }
}

// ---------------- persistent MFMA encoder: 64 blocks (dir = bid>>5, nb = bid&31) ----------------
// Per block: 64 gate-interleaved cols; 4 waves = 2M x 2N fragment split.
// U-slice lives in REGISTERS (32 bf16x8 per wave) for all 128 steps.
__global__ __launch_bounds__(256, 1) void k_enc_mfma(
    const float* __restrict__ xWf, const float* __restrict__ xWb,
    const __hip_bfloat16* __restrict__ Utf, const __hip_bfloat16* __restrict__ Utb,
    __hip_bfloat16* __restrict__ hs_f, __hip_bfloat16* __restrict__ hs_b,
    __hip_bfloat16* __restrict__ henc,
    float* __restrict__ cf, float* __restrict__ cb,
    unsigned* ctr, unsigned* flag) {
  const int bid = blockIdx.x;
  const int dir = bid >> 5, nb = bid & 31;
  const int c0 = nb * 64;
  const float* xW = dir ? xWb : xWf;
  const __hip_bfloat16* Ut = dir ? Utb : Utf;
  __hip_bfloat16* hs = dir ? hs_b : hs_f;
  __hip_bfloat16* hcur = henc + (size_t)dir * 32768;   // [2][32][512] bf16
  float* cOut = dir ? cb : cf;

  __shared__ __hip_bfloat16 Hs[32][520];
  __shared__ float Zs[32][68];

  const int tid = threadIdx.x;
  const int lane = tid & 63;
  const int wv = tid >> 6;
  const int wm = wv >> 1, wn = wv & 1;
  const int fr = lane & 15;
  const int fq = lane >> 4;

  // loop-invariant B fragments (U-slice) in registers
  bf16x8 bfrag[2][16];
#pragma unroll
  for (int n = 0; n < 2; ++n)
#pragma unroll
    for (int kk = 0; kk < 16; ++kk)
      bfrag[n][kk] = *(const bf16x8*)(Ut + (size_t)(c0 + (wn * 2 + n) * 16 + fr) * 512 + kk * 32 + fq * 8);

  const int b0 = tid >> 4;        // item0 batch 0..15 (item1 = b0+16)
  const int jj = tid & 15;
  const int jglob = nb * 16 + jj;
  float cs0 = 0.f, cs1 = 0.f;

  for (int t = 0; t < 128; ++t) {
    const int trow = dir ? (127 - t) : t;
    if (t > 0) {
      const __hip_bfloat16* hsrc = hcur + (size_t)((t + 1) & 1) * 16384;
#pragma unroll
      for (int i = 0; i < 8; ++i) {
        int c = tid + i * 256;
        int r = c >> 6, cc = (c & 63) * 8;
        *(bf16x8*)&Hs[r][cc] = *(const bf16x8*)(hsrc + (size_t)r * 512 + cc);
      }
    }
    __syncthreads();
    if (t > 0) {
      f32x4 acc0 = {}, acc1 = {};
#pragma unroll
      for (int kk = 0; kk < 16; ++kk) {
        bf16x8 a = *(const bf16x8*)&Hs[wm * 16 + fr][kk * 32 + fq * 8];
        acc0 = __builtin_amdgcn_mfma_f32_16x16x32_bf16(a, bfrag[0][kk], acc0, 0, 0, 0);
        acc1 = __builtin_amdgcn_mfma_f32_16x16x32_bf16(a, bfrag[1][kk], acc1, 0, 0, 0);
      }
#pragma unroll
      for (int r = 0; r < 4; ++r) {
        Zs[wm * 16 + fq * 4 + r][(wn * 2 + 0) * 16 + fr] = acc0[r];
        Zs[wm * 16 + fq * 4 + r][(wn * 2 + 1) * 16 + fr] = acc1[r];
      }
    }
    __syncthreads();
    {
      float4 z = *(const float4*)(xW + ((size_t)(trow * 32 + b0)) * 2048 + c0 + 4 * jj);
      if (t > 0) { float4 q = *(const float4*)&Zs[b0][4 * jj]; z.x += q.x; z.y += q.y; z.z += q.z; z.w += q.w; }
      cs0 = sigm(z.y) * cs0 + sigm(z.x) * tanhf(z.z);
      float h = sigm(z.w) * tanhf(cs0);
      hcur[(size_t)(t & 1) * 16384 + (size_t)b0 * 512 + jglob] = __float2bfloat16(h);
      hs[((size_t)trow * 32 + b0) * 512 + jglob] = __float2bfloat16(h);
    }
    {
      int b1 = b0 + 16;
      float4 z = *(const float4*)(xW + ((size_t)(trow * 32 + b1)) * 2048 + c0 + 4 * jj);
      if (t > 0) { float4 q = *(const float4*)&Zs[b1][4 * jj]; z.x += q.x; z.y += q.y; z.z += q.z; z.w += q.w; }
      cs1 = sigm(z.y) * cs1 + sigm(z.x) * tanhf(z.z);
      float h = sigm(z.w) * tanhf(cs1);
      hcur[(size_t)(t & 1) * 16384 + (size_t)b1 * 512 + jglob] = __float2bfloat16(h);
      hs[((size_t)trow * 32 + b1) * 512 + jglob] = __float2bfloat16(h);
    }
    if (t < 127) gridbar(ctr, flag, 64u, (unsigned)(t + 1));
  }
  cOut[(size_t)b0 * 512 + jglob] = cs0;
  cOut[(size_t)(b0 + 16) * 512 + jglob] = cs1;
}

// ---------------- persistent MFMA decoder recurrence: 32 blocks, 63 steps ----------------
__global__ __launch_bounds__(256, 1) void k_dec_mfma(
    const float* __restrict__ yW, const __hip_bfloat16* __restrict__ Utd,
    const float* __restrict__ prev_c,
    __hip_bfloat16* __restrict__ hdec, float* __restrict__ dec,
    unsigned* ctr, unsigned* flag) {
  const int nb = blockIdx.x;
  const int c0 = nb * 64;

  __shared__ __hip_bfloat16 Hs[32][520];
  __shared__ float Zs[32][68];

  const int tid = threadIdx.x;
  const int lane = tid & 63;
  const int wv = tid >> 6;
  const int wm = wv >> 1, wn = wv & 1;
  const int fr = lane & 15;
  const int fq = lane >> 4;

  bf16x8 bfrag[2][16];
#pragma unroll
  for (int n = 0; n < 2; ++n)
#pragma unroll
    for (int kk = 0; kk < 16; ++kk)
      bfrag[n][kk] = *(const bf16x8*)(Utd + (size_t)(c0 + (wn * 2 + n) * 16 + fr) * 512 + kk * 32 + fq * 8);

  const int b0 = tid >> 4;
  const int jj = tid & 15;
  const int jglob = nb * 16 + jj;
  float cs0 = prev_c[(size_t)b0 * 512 + jglob];
  float cs1 = prev_c[(size_t)(b0 + 16) * 512 + jglob];

  for (int t = 0; t < cTM1; ++t) {
    const __hip_bfloat16* hsrc = hdec + (size_t)((t + 1) & 1) * 16384;  // t=0: buf1 = prev_h
#pragma unroll
    for (int i = 0; i < 8; ++i) {
      int c = tid + i * 256;
      int r = c >> 6, cc = (c & 63) * 8;
      *(bf16x8*)&Hs[r][cc] = *(const bf16x8*)(hsrc + (size_t)r * 512 + cc);
    }
    __syncthreads();
    {
      f32x4 acc0 = {}, acc1 = {};
#pragma unroll
      for (int kk = 0; kk < 16; ++kk) {
        bf16x8 a = *(const bf16x8*)&Hs[wm * 16 + fr][kk * 32 + fq * 8];
        acc0 = __builtin_amdgcn_mfma_f32_16x16x32_bf16(a, bfrag[0][kk], acc0, 0, 0, 0);
        acc1 = __builtin_amdgcn_mfma_f32_16x16x32_bf16(a, bfrag[1][kk], acc1, 0, 0, 0);
      }
#pragma unroll
      for (int r = 0; r < 4; ++r) {
        Zs[wm * 16 + fq * 4 + r][(wn * 2 + 0) * 16 + fr] = acc0[r];
        Zs[wm * 16 + fq * 4 + r][(wn * 2 + 1) * 16 + fr] = acc1[r];
      }
    }
    __syncthreads();
    {
      float4 z = *(const float4*)(yW + ((size_t)(t * 32 + b0)) * 2048 + c0 + 4 * jj);
      float4 q = *(const float4*)&Zs[b0][4 * jj];
      z.x += q.x; z.y += q.y; z.z += q.z; z.w += q.w;
      cs0 = sigm(z.y) * cs0 + sigm(z.x) * tanhf(z.z);
      float h = sigm(z.w) * tanhf(cs0);
      hdec[(size_t)(t & 1) * 16384 + (size_t)b0 * 512 + jglob] = __float2bfloat16(h);
      dec[((size_t)b0 * cTM1 + t) * 1024 + 512 + jglob] = h;
    }
    {
      int b1 = b0 + 16;
      float4 z = *(const float4*)(yW + ((size_t)(t * 32 + b1)) * 2048 + c0 + 4 * jj);
      float4 q = *(const float4*)&Zs[b1][4 * jj];
      z.x += q.x; z.y += q.y; z.z += q.z; z.w += q.w;
      cs1 = sigm(z.y) * cs1 + sigm(z.x) * tanhf(z.z);
      float h = sigm(z.w) * tanhf(cs1);
      hdec[(size_t)(t & 1) * 16384 + (size_t)b1 * 512 + jglob] = __float2bfloat16(h);
      dec[((size_t)b1 * cTM1 + t) * 1024 + 512 + jglob] = h;
    }
    if (t < cTM1 - 1) gridbar(ctr, flag, 32u, (unsigned)(t + 1));
  }
}

// ---------------- concat builder (bf16 hs sources, zero-padded to 4224 rows) ----------------
__global__ __launch_bounds__(128) void k_cat_bf(const __hip_bfloat16* __restrict__ hs_f,
                                                const __hip_bfloat16* __restrict__ hs_b,
                                                const float* __restrict__ cf,
                                                const float* __restrict__ cb,
                                                __hip_bfloat16* __restrict__ cat) {
  int r = blockIdx.x;
  int tid = threadIdx.x;
  __hip_bfloat16* drow = cat + (size_t)r * 1024 + tid * 8;
  if (r >= 4160) {
    bf16x8 zv = {};
    *(bf16x8*)drow = zv;
    return;
  }
  if (r < 4128) {
    const __hip_bfloat16 *pf, *pb;
    if (r < 4096) {
      int b = r >> 7, s = r & 127;
      pf = hs_f + ((size_t)s * 32 + b) * 512;
      pb = hs_b + ((size_t)s * 32 + b) * 512;
    } else {
      int b = r - 4096;
      pf = hs_f + ((size_t)127 * 32 + b) * 512;   // final fwd h
      pb = hs_b + ((size_t)b) * 512;              // final bwd h (position 0)
    }
    const __hip_bfloat16* s8 = (tid < 64) ? (pf + tid * 8) : (pb + (tid - 64) * 8);
    *(bf16x8*)drow = *(const bf16x8*)s8;
  } else {
    int b = r - 4128;
    const float* s8 = (tid < 64) ? (cf + (size_t)b * 512 + tid * 8)
                                 : (cb + (size_t)b * 512 + (tid - 64) * 8);
    bf16x8 v;
#pragma unroll
    for (int i = 0; i < 8; ++i) v[i] = (__bf16)s8[i];
    *(bf16x8*)drow = v;
  }
}

// ---------------- batched attention over all (b,t) ----------------
__global__ __launch_bounds__(256) void k_attn_all(const float* __restrict__ src_h,
                                                  const float* __restrict__ neg,
                                                  float* __restrict__ dec) {
  int bid = blockIdx.x;               // 0..2015, XCD-localized by batch
  int xcd = bid & 7, idx = bid >> 3;
  int b = xcd + 8 * (idx / 63);
  int t = idx % 63;
  int tx = threadIdx.x;
  __shared__ float hv[cH];
  __shared__ float part[256];
  __shared__ float sc[cS];
  __shared__ float red[cS];
  float* drow = dec + ((size_t)b * cTM1 + t) * (2 * cH);
  hv[tx] = drow[cH + tx];
  hv[tx + 256] = drow[cH + tx + 256];
  __syncthreads();
  {
    int s = tx >> 1, half = tx & 1;
    const float4* sr = (const float4*)(src_h + ((size_t)b * cS + s) * cH + half * 256);
    const float4* hh = (const float4*)(hv + half * 256);
    float acc = 0.f;
#pragma unroll 8
    for (int k = 0; k < 64; ++k) {
      float4 v = sr[k], h4 = hh[k];
      acc += v.x * h4.x + v.y * h4.y + v.z * h4.z + v.w * h4.w;
    }
    part[tx] = acc;
  }
  __syncthreads();
  if (tx < cS) {
    float s0 = part[2 * tx] + part[2 * tx + 1] + neg[b * cS + tx];
    sc[tx] = s0;
    red[tx] = s0;
  }
  __syncthreads();
  for (int off = 64; off >= 1; off >>= 1) {
    if (tx < off) red[tx] = fmaxf(red[tx], red[tx + off]);
    __syncthreads();
  }
  float mx = red[0];
  __syncthreads();
  float e = 0.f;
  if (tx < cS) { e = expf(sc[tx] - mx); red[tx] = e; }
  __syncthreads();
  for (int off = 64; off >= 1; off >>= 1) {
    if (tx < off) red[tx] += red[tx + off];
    __syncthreads();
  }
  float inv = 1.0f / red[0];
  __syncthreads();
  if (tx < cS) sc[tx] = e * inv;
  __syncthreads();
  float a0 = 0.f, a1 = 0.f;
  for (int s = 0; s < cS; ++s) {
    float w = sc[s];
    const float* sr = src_h + ((size_t)b * cS + s) * cH;
    a0 += w * sr[tx];
    a1 += w * sr[tx + 256];
  }
  drow[tx] = a0;
  drow[tx + 256] = a1;
}

extern "C" void kernel_launch(void* const* d_in, const int* in_sizes, int n_in,
                              void* d_out, int out_size, void* d_ws, size_t ws_size,
                              hipStream_t stream) {
  const int* src = (const int*)d_in[0];
  const int* trg = (const int*)d_in[1];
  const float* E_src = (const float*)d_in[2];
  const float* E_trg = (const float*)d_in[3];
  const float* Wf = (const float*)d_in[4];
  const float* Uf = (const float*)d_in[5];
  const float* bf = (const float*)d_in[6];
  const float* Wb = (const float*)d_in[7];
  const float* Ub = (const float*)d_in[8];
  const float* bb = (const float*)d_in[9];
  const float* Wd = (const float*)d_in[10];
  const float* Ud = (const float*)d_in[11];
  const float* bd = (const float*)d_in[12];
  const float* fcW = (const float*)d_in[13];
  const float* fcb = (const float*)d_in[14];
  const float* clsW = (const float*)d_in[15];
  const float* clsb = (const float*)d_in[16];
  float* out = (float*)d_out;
  float* ws = (float*)d_ws;

  // ---- static layout (float offsets), total 35.2M floats < R1-proven 36.7M ----
  float* xWf = ws;                                  // 8388608
  float* xWb = ws + 8388608;                        // 8388608   -> 16777216
  float* yW = ws + 16777216;                        // 4128768   -> 20905984
  __hip_bfloat16* hs_f = (__hip_bfloat16*)(ws + 20905984);   // [128][32][512] bf16 (1048576 fl)
  __hip_bfloat16* hs_b = (__hip_bfloat16*)(ws + 21954560);   // 1048576 fl -> 23003136
  float* cf = ws + 23003136;                        // 16384
  float* cb = ws + 23019520;                        // 16384
  float* neg = ws + 23035904;                       // 4096      -> 23040000
  float* fco = ws + 23040000;                       // 2129920   -> 25169920
  float* dec = ws + 25169920;                       // 2064384   -> 27234304
  __hip_bfloat16* Utd = (__hip_bfloat16*)(ws + 27234304);    // 524288 fl -> 27758592
  __hip_bfloat16* henc = (__hip_bfloat16*)(ws + 27758592);   // 65536 fl  -> 27824128
  __hip_bfloat16* hdec = (__hip_bfloat16*)(ws + 27824128);   // 32768 fl  -> 27856896
  unsigned* bars = (unsigned*)(ws + 27856896);      // 64 fl     -> 27856960
  float* pool = ws + 27856960;                      // ~8.8M floats

  // pool transients
  float* xs = pool;                                           // 2097152
  float* ys = pool + 2097152;                                 // 1032192 -> 3129344
  __hip_bfloat16* Utf = (__hip_bfloat16*)(pool + 3145728);    // 524288  -> 3670016
  __hip_bfloat16* Utb = (__hip_bfloat16*)(pool + 3670016);    // 524288  -> 4194304
  __hip_bfloat16* xs_bf = (__hip_bfloat16*)(pool + 4194304);  // 1048576 -> 5242880
  __hip_bfloat16* ys_bf = (__hip_bfloat16*)(pool + 5242880);  // 524288  -> 5767168
  __hip_bfloat16* Wtfx = (__hip_bfloat16*)(pool + 5767168);   // 524288  -> 6291456
  __hip_bfloat16* Wtbx = (__hip_bfloat16*)(pool + 6291456);   // 524288  -> 6815744
  __hip_bfloat16* Wtdx = (__hip_bfloat16*)(pool + 6815744);   // 524288  -> 7340032
  float* bfx = pool + 7340032;                                // 2048
  float* bbx = pool + 7342080;                                // 2048
  float* bdx = pool + 7344128;                                // 2048    -> 7346176
  // post-encoder aliases (xs/ys dead)
  __hip_bfloat16* cat_bf = (__hip_bfloat16*)pool;             // 4224x1024 bf16 (2162688 fl)
  __hip_bfloat16* fcWt = (__hip_bfloat16*)(pool + 2162688);   // 262144 fl
  __hip_bfloat16* clsWt = (__hip_bfloat16*)xWf;               // 32000x1024 bf16 (spans xWf+xWb)
  __hip_bfloat16* dec_bf = (__hip_bfloat16*)pool;             // 2048x1024 bf16 (phase F)

  // phase A: embeddings, conversions, weight prep
  k_embed_src<<<4096, 128, 0, stream>>>(src, E_src, xs, neg);
  k_embed_trg<<<2016, 128, 0, stream>>>(trg, E_trg, ys);
  k_f2b<<<8192, 256, 0, stream>>>(xs, xs_bf, 4096 * 512, 4096 * 512);
  k_f2b<<<4096, 256, 0, stream>>>(ys, ys_bf, 2016 * 512, 2048 * 512);
  k_f2bT<<<dim3(64, 16), 256, 0, stream>>>(Wf, Wtfx, 512, 2048, 1);
  k_f2bT<<<dim3(64, 16), 256, 0, stream>>>(Wb, Wtbx, 512, 2048, 1);
  k_f2bT<<<dim3(64, 16), 256, 0, stream>>>(Wd, Wtdx, 512, 2048, 1);
  k_f2bT<<<dim3(64, 16), 256, 0, stream>>>(Uf, Utf, 512, 2048, 1);
  k_f2bT<<<dim3(64, 16), 256, 0, stream>>>(Ub, Utb, 512, 2048, 1);
  k_f2bT<<<dim3(64, 16), 256, 0, stream>>>(Ud, Utd, 512, 2048, 1);
  k_permb<<<8, 256, 0, stream>>>(bf, bfx);
  k_permb<<<8, 256, 0, stream>>>(bb, bbx);
  k_permb<<<8, 256, 0, stream>>>(bd, bdx);

  // input projections (gate-interleaved columns, bias folded)
  k_bgemm<<<dim3(32, 16), 256, 0, stream>>>(xs_bf, Wtfx, bfx, xWf, 4096, 512, 2048);
  k_bgemm<<<dim3(32, 16), 256, 0, stream>>>(xs_bf, Wtbx, bbx, xWb, 4096, 512, 2048);
  k_bgemm<<<dim3(16, 16), 256, 0, stream>>>(ys_bf, Wtdx, bdx, yW, 2016, 512, 2048);

  // phase B: persistent MFMA encoder
  k_init_bars<<<1, 64, 0, stream>>>(bars);
  k_enc_mfma<<<64, 256, 0, stream>>>(xWf, xWb, Utf, Utb, hs_f, hs_b, henc, cf, cb,
                                     bars + 0, bars + 1);

  // phase C: concat + fc projection (bf16 MFMA)
  k_cat_bf<<<4224, 128, 0, stream>>>(hs_f, hs_b, cf, cb, cat_bf);
  k_f2bT<<<dim3(16, 32), 256, 0, stream>>>(fcW, fcWt, 1024, 512, 0);
  k_bgemm<<<dim3(33, 4), 256, 0, stream>>>(cat_bf, fcWt, fcb, fco, 4160, 1024, 512);

  // classifier weight convert (xWf/xWb dead after encoder)
  k_f2bT<<<dim3(1000, 32), 256, 0, stream>>>(clsW, clsWt, 1024, 32000, 0);

  // phase D: persistent MFMA decoder recurrence, then batched attention
  const float* prev_h = fco + (size_t)4096 * 512;
  const float* prev_c = fco + (size_t)4128 * 512;
  k_f2b<<<64, 256, 0, stream>>>(prev_h, hdec + 16384, 16384, 16384);  // h0 -> buf1
  k_dec_mfma<<<32, 256, 0, stream>>>(yW, Utd, prev_c, hdec, dec, bars + 2, bars + 3);
  k_attn_all<<<2016, 256, 0, stream>>>(fco, neg, dec);

  // phase F: classifier
  k_f2b<<<8192, 256, 0, stream>>>(dec, dec_bf, 2016 * 1024, 2048 * 1024);
  k_bgemm<<<dim3(16, 250), 256, 0, stream>>>(dec_bf, clsWt, clsb, out, 2016, 1024, 32000);
}

// Round 6
// 1691.778 us; speedup vs baseline: 5.4890x; 1.0484x over previous
//
#include <hip/hip_runtime.h>
#include <hip/hip_bf16.h>
#include <stdint.h>

constexpr int cB = 32, cS = 128, cT = 64, cH = 512, cH4 = 2048, cVT = 32000, cTM1 = 63;

typedef __attribute__((ext_vector_type(8))) __bf16 bf16x8;
typedef __attribute__((ext_vector_type(4))) float f32x4;

__device__ __forceinline__ float sigm(float x) { return 1.0f / (1.0f + expf(-x)); }

// ---------------- device-scope grid barrier (release/acquire fences) ----------------
__device__ __forceinline__ void gridbar(unsigned* ctr, unsigned* flag,
                                        unsigned nblk, unsigned gen) {
  __syncthreads();
  if (threadIdx.x == 0) {
    __builtin_amdgcn_fence(__ATOMIC_RELEASE, "agent");   // wbL2: make h stores visible
    unsigned old = __hip_atomic_fetch_add(ctr, 1u, __ATOMIC_RELAXED,
                                          __HIP_MEMORY_SCOPE_AGENT);
    if (old == gen * nblk - 1u) {
      __hip_atomic_store(flag, gen, __ATOMIC_RELAXED, __HIP_MEMORY_SCOPE_AGENT);
    } else {
      while (__hip_atomic_load(flag, __ATOMIC_RELAXED, __HIP_MEMORY_SCOPE_AGENT) < gen)
        __builtin_amdgcn_s_sleep(2);
    }
    __builtin_amdgcn_fence(__ATOMIC_ACQUIRE, "agent");   // inv: see other blocks' h
  }
  __syncthreads();
}

__global__ __launch_bounds__(64) void k_init_bars(unsigned* p) {
  if (threadIdx.x < 16) p[threadIdx.x] = 0u;
}

// ---------------- embeddings (write bf16 directly) ----------------
__global__ __launch_bounds__(128) void k_embed_src(const int* __restrict__ src,
                                                   const float* __restrict__ E,
                                                   __hip_bfloat16* __restrict__ xs_bf,
                                                   float* __restrict__ neg) {
  int sb = blockIdx.x;            // s*B + b
  int s = sb >> 5, b = sb & 31;
  int tok = src[b * cS + s];
  float4 e = ((const float4*)(E + (size_t)tok * cH))[threadIdx.x];
  __hip_bfloat16* drow = xs_bf + (size_t)sb * cH + threadIdx.x * 4;
  drow[0] = __float2bfloat16(e.x); drow[1] = __float2bfloat16(e.y);
  drow[2] = __float2bfloat16(e.z); drow[3] = __float2bfloat16(e.w);
  if (threadIdx.x == 0) neg[b * cS + s] = (tok == 0) ? -1e9f : 0.0f;
}

__global__ __launch_bounds__(128) void k_embed_trg(const int* __restrict__ trg,
                                                   const float* __restrict__ E,
                                                   __hip_bfloat16* __restrict__ ys_bf) {
  int tb = blockIdx.x;            // t*B + b, t < 63
  int t = tb >> 5, b = tb & 31;
  int tok = trg[b * cT + t];
  float4 e = ((const float4*)(E + (size_t)tok * cH))[threadIdx.x];
  __hip_bfloat16* drow = ys_bf + (size_t)tb * cH + threadIdx.x * 4;
  drow[0] = __float2bfloat16(e.x); drow[1] = __float2bfloat16(e.y);
  drow[2] = __float2bfloat16(e.z); drow[3] = __float2bfloat16(e.w);
}

// ---------------- fp32 -> bf16 elementwise ----------------
__global__ __launch_bounds__(256) void k_f2b(const float* __restrict__ src,
                                             __hip_bfloat16* __restrict__ dst,
                                             int srcN, int dstN) {
  int i = blockIdx.x * 256 + threadIdx.x;
  if (i < dstN) {
    float v = (i < srcN) ? src[i] : 0.0f;
    dst[i] = __float2bfloat16(v);
  }
}

// ---------------- fp32 [K][N] -> bf16 [N][K] transpose-convert ----------------
// gi=1: permute output row n -> (n&511)*4 + (n>>9)  (gate interleave)
__global__ __launch_bounds__(256) void k_f2bT(const float* __restrict__ src,
                                              __hip_bfloat16* __restrict__ dst,
                                              int K, int N, int gi) {
  __shared__ float t[32][33];
  int nt = blockIdx.x * 32, kt = blockIdx.y * 32;
  int c = threadIdx.x & 31, r0 = threadIdx.x >> 5;
#pragma unroll
  for (int i = 0; i < 4; ++i) {
    int r = r0 + i * 8;
    t[r][c] = src[(size_t)(kt + r) * N + nt + c];
  }
  __syncthreads();
#pragma unroll
  for (int i = 0; i < 4; ++i) {
    int row = nt + r0 + i * 8;
    int pr = gi ? (((row & 511) << 2) | (row >> 9)) : row;
    dst[(size_t)pr * K + kt + c] = __float2bfloat16(t[c][r0 + i * 8]);
  }
}

// ---------------- bias gate-interleave: out[j*4+g] = in[g*512+j] ----------------
__global__ __launch_bounds__(256) void k_permb(const float* __restrict__ in,
                                               float* __restrict__ out) {
  int i = blockIdx.x * 256 + threadIdx.x;   // 0..2047
  out[i] = in[(i & 3) * 512 + (i >> 2)];
}

// ---------------- bf16 MFMA GEMM: C[M,N] = A[M,K] @ Bt[N,K]^T + bias ----------------
__global__ __launch_bounds__(256) void k_bgemm(const __hip_bfloat16* __restrict__ A,
                                               const __hip_bfloat16* __restrict__ Bt,
                                               const float* __restrict__ bias,
                                               float* __restrict__ C,
                                               int M, int K, int N) {
  __shared__ __hip_bfloat16 As[128 * 64];
  __shared__ __hip_bfloat16 Bs[128 * 64];
  const int tid = threadIdx.x;
  const int lane = tid & 63;
  const int wave = tid >> 6;
  const int wr = wave >> 1, wc = wave & 1;
  const int bm = blockIdx.x * 128, bn = blockIdx.y * 128;

  f32x4 acc[4][4] = {};

  const int srow = lane >> 3;
  const int scol = (lane & 7) * 8;

  for (int kt = 0; kt < K; kt += 64) {
#pragma unroll
    for (int i = 0; i < 4; ++i) {
      int c = wave * 4 + i;
      const __hip_bfloat16* ga = A + (size_t)(bm + c * 8 + srow) * K + kt + scol;
      __builtin_amdgcn_global_load_lds(
          (const __attribute__((address_space(1))) uint32_t*)ga,
          (__attribute__((address_space(3))) uint32_t*)(As + c * 512), 16, 0, 0);
      const __hip_bfloat16* gb = Bt + (size_t)(bn + c * 8 + srow) * K + kt + scol;
      __builtin_amdgcn_global_load_lds(
          (const __attribute__((address_space(1))) uint32_t*)gb,
          (__attribute__((address_space(3))) uint32_t*)(Bs + c * 512), 16, 0, 0);
    }
    __syncthreads();

#pragma unroll
    for (int kk = 0; kk < 64; kk += 32) {
      const int ko = kk + (lane >> 4) * 8;
      bf16x8 a[4], b[4];
      const int ar = wr * 64 + (lane & 15);
#pragma unroll
      for (int m = 0; m < 4; ++m)
        a[m] = *(const bf16x8*)(As + (size_t)(ar + m * 16) * 64 + ko);
      const int br = wc * 64 + (lane & 15);
#pragma unroll
      for (int n = 0; n < 4; ++n)
        b[n] = *(const bf16x8*)(Bs + (size_t)(br + n * 16) * 64 + ko);
#pragma unroll
      for (int m = 0; m < 4; ++m)
#pragma unroll
        for (int n = 0; n < 4; ++n)
          acc[m][n] = __builtin_amdgcn_mfma_f32_16x16x32_bf16(a[m], b[n], acc[m][n], 0, 0, 0);
    }
    __syncthreads();
  }

#pragma unroll
  for (int m = 0; m < 4; ++m) {
    const int row0 = bm + wr * 64 + m * 16 + (lane >> 4) * 4;
#pragma unroll
    for (int n = 0; n < 4; ++n) {
      const int col = bn + wc * 64 + n * 16 + (lane & 15);
      const float bv = bias[col];
#pragma unroll
      for (int r = 0; r < 4; ++r) {
        const int row = row0 + r;
        if (row < M) C[(size_t)row * N + col] = acc[m][n][r] + bv;
      }
    }
  }
}

// ---------------- persistent MFMA encoder: 64 blocks, PER-DIR barriers ----------------
__global__ __launch_bounds__(256, 1) void k_enc_mfma(
    const float* __restrict__ xWf, const float* __restrict__ xWb,
    const __hip_bfloat16* __restrict__ Utf, const __hip_bfloat16* __restrict__ Utb,
    __hip_bfloat16* __restrict__ hs_f, __hip_bfloat16* __restrict__ hs_b,
    __hip_bfloat16* __restrict__ henc,
    float* __restrict__ cf, float* __restrict__ cb,
    unsigned* bars) {
  const int bid = blockIdx.x;
  const int dir = bid >> 5, nb = bid & 31;
  const int c0 = nb * 64;
  const float* xW = dir ? xWb : xWf;
  const __hip_bfloat16* Ut = dir ? Utb : Utf;
  __hip_bfloat16* hs = dir ? hs_b : hs_f;
  __hip_bfloat16* hcur = henc + (size_t)dir * 32768;   // [2][32][512] bf16
  float* cOut = dir ? cb : cf;
  unsigned* ctr = bars + dir * 2;
  unsigned* flag = bars + dir * 2 + 1;

  __shared__ __hip_bfloat16 Hs[32][520];
  __shared__ float Zs[32][68];

  const int tid = threadIdx.x;
  const int lane = tid & 63;
  const int wv = tid >> 6;
  const int wm = wv >> 1, wn = wv & 1;
  const int fr = lane & 15;
  const int fq = lane >> 4;

  // loop-invariant B fragments (U-slice) in registers
  bf16x8 bfrag[2][16];
#pragma unroll
  for (int n = 0; n < 2; ++n)
#pragma unroll
    for (int kk = 0; kk < 16; ++kk)
      bfrag[n][kk] = *(const bf16x8*)(Ut + (size_t)(c0 + (wn * 2 + n) * 16 + fr) * 512 + kk * 32 + fq * 8);

  const int b0 = tid >> 4;        // item0 batch 0..15 (item1 = b0+16)
  const int jj = tid & 15;
  const int jglob = nb * 16 + jj;
  float cs0 = 0.f, cs1 = 0.f;

  // prefetch z for t=0
  const int trow0 = dir ? 127 : 0;
  float4 z0 = *(const float4*)(xW + ((size_t)(trow0 * 32 + b0)) * 2048 + c0 + 4 * jj);
  float4 z1 = *(const float4*)(xW + ((size_t)(trow0 * 32 + b0 + 16)) * 2048 + c0 + 4 * jj);

  for (int t = 0; t < 128; ++t) {
    const int trow = dir ? (127 - t) : t;
    if (t > 0) {
      const __hip_bfloat16* hsrc = hcur + (size_t)((t + 1) & 1) * 16384;
#pragma unroll
      for (int i = 0; i < 8; ++i) {
        int c = tid + i * 256;
        int r = c >> 6, cc = (c & 63) * 8;
        *(bf16x8*)&Hs[r][cc] = *(const bf16x8*)(hsrc + (size_t)r * 512 + cc);
      }
    }
    __syncthreads();
    if (t > 0) {
      f32x4 acc0 = {}, acc1 = {};
#pragma unroll
      for (int kk = 0; kk < 16; ++kk) {
        bf16x8 a = *(const bf16x8*)&Hs[wm * 16 + fr][kk * 32 + fq * 8];
        acc0 = __builtin_amdgcn_mfma_f32_16x16x32_bf16(a, bfrag[0][kk], acc0, 0, 0, 0);
        acc1 = __builtin_amdgcn_mfma_f32_16x16x32_bf16(a, bfrag[1][kk], acc1, 0, 0, 0);
      }
#pragma unroll
      for (int r = 0; r < 4; ++r) {
        Zs[wm * 16 + fq * 4 + r][(wn * 2 + 0) * 16 + fr] = acc0[r];
        Zs[wm * 16 + fq * 4 + r][(wn * 2 + 1) * 16 + fr] = acc1[r];
      }
    }
    __syncthreads();
    {
      float4 z = z0;
      if (t > 0) { float4 q = *(const float4*)&Zs[b0][4 * jj]; z.x += q.x; z.y += q.y; z.z += q.z; z.w += q.w; }
      cs0 = sigm(z.y) * cs0 + sigm(z.x) * tanhf(z.z);
      float h = sigm(z.w) * tanhf(cs0);
      __hip_bfloat16 hb = __float2bfloat16(h);
      hcur[(size_t)(t & 1) * 16384 + (size_t)b0 * 512 + jglob] = hb;
      hs[((size_t)trow * 32 + b0) * 512 + jglob] = hb;
    }
    {
      int b1 = b0 + 16;
      float4 z = z1;
      if (t > 0) { float4 q = *(const float4*)&Zs[b1][4 * jj]; z.x += q.x; z.y += q.y; z.z += q.z; z.w += q.w; }
      cs1 = sigm(z.y) * cs1 + sigm(z.x) * tanhf(z.z);
      float h = sigm(z.w) * tanhf(cs1);
      __hip_bfloat16 hb = __float2bfloat16(h);
      hcur[(size_t)(t & 1) * 16384 + (size_t)(b0 + 16) * 512 + jglob] = hb;
      hs[((size_t)trow * 32 + b0 + 16) * 512 + jglob] = hb;
    }
    if (t < 127) {
      // prefetch next step's xW fragment BEFORE the barrier (latency hides in wait)
      const int ntrow = dir ? (126 - t) : (t + 1);
      z0 = *(const float4*)(xW + ((size_t)(ntrow * 32 + b0)) * 2048 + c0 + 4 * jj);
      z1 = *(const float4*)(xW + ((size_t)(ntrow * 32 + b0 + 16)) * 2048 + c0 + 4 * jj);
      gridbar(ctr, flag, 32u, (unsigned)(t + 1));
    }
  }
  cOut[(size_t)b0 * 512 + jglob] = cs0;
  cOut[(size_t)(b0 + 16) * 512 + jglob] = cs1;
}

// ---------------- persistent MFMA decoder recurrence: 32 blocks, 63 steps ----------------
// writes h directly as bf16 into dec_bf rows [b*63+t][512..1024]
__global__ __launch_bounds__(256, 1) void k_dec_mfma(
    const float* __restrict__ yW, const __hip_bfloat16* __restrict__ Utd,
    const float* __restrict__ prev_c,
    __hip_bfloat16* __restrict__ hdec, __hip_bfloat16* __restrict__ decb,
    unsigned* ctr, unsigned* flag) {
  const int nb = blockIdx.x;
  const int c0 = nb * 64;

  __shared__ __hip_bfloat16 Hs[32][520];
  __shared__ float Zs[32][68];

  const int tid = threadIdx.x;
  const int lane = tid & 63;
  const int wv = tid >> 6;
  const int wm = wv >> 1, wn = wv & 1;
  const int fr = lane & 15;
  const int fq = lane >> 4;

  bf16x8 bfrag[2][16];
#pragma unroll
  for (int n = 0; n < 2; ++n)
#pragma unroll
    for (int kk = 0; kk < 16; ++kk)
      bfrag[n][kk] = *(const bf16x8*)(Utd + (size_t)(c0 + (wn * 2 + n) * 16 + fr) * 512 + kk * 32 + fq * 8);

  const int b0 = tid >> 4;
  const int jj = tid & 15;
  const int jglob = nb * 16 + jj;
  float cs0 = prev_c[(size_t)b0 * 512 + jglob];
  float cs1 = prev_c[(size_t)(b0 + 16) * 512 + jglob];

  float4 z0 = *(const float4*)(yW + ((size_t)b0) * 2048 + c0 + 4 * jj);
  float4 z1 = *(const float4*)(yW + ((size_t)(b0 + 16)) * 2048 + c0 + 4 * jj);

  for (int t = 0; t < cTM1; ++t) {
    const __hip_bfloat16* hsrc = hdec + (size_t)((t + 1) & 1) * 16384;  // t=0: buf1 = prev_h
#pragma unroll
    for (int i = 0; i < 8; ++i) {
      int c = tid + i * 256;
      int r = c >> 6, cc = (c & 63) * 8;
      *(bf16x8*)&Hs[r][cc] = *(const bf16x8*)(hsrc + (size_t)r * 512 + cc);
    }
    __syncthreads();
    {
      f32x4 acc0 = {}, acc1 = {};
#pragma unroll
      for (int kk = 0; kk < 16; ++kk) {
        bf16x8 a = *(const bf16x8*)&Hs[wm * 16 + fr][kk * 32 + fq * 8];
        acc0 = __builtin_amdgcn_mfma_f32_16x16x32_bf16(a, bfrag[0][kk], acc0, 0, 0, 0);
        acc1 = __builtin_amdgcn_mfma_f32_16x16x32_bf16(a, bfrag[1][kk], acc1, 0, 0, 0);
      }
#pragma unroll
      for (int r = 0; r < 4; ++r) {
        Zs[wm * 16 + fq * 4 + r][(wn * 2 + 0) * 16 + fr] = acc0[r];
        Zs[wm * 16 + fq * 4 + r][(wn * 2 + 1) * 16 + fr] = acc1[r];
      }
    }
    __syncthreads();
    {
      float4 z = z0;
      float4 q = *(const float4*)&Zs[b0][4 * jj];
      z.x += q.x; z.y += q.y; z.z += q.z; z.w += q.w;
      cs0 = sigm(z.y) * cs0 + sigm(z.x) * tanhf(z.z);
      float h = sigm(z.w) * tanhf(cs0);
      __hip_bfloat16 hb = __float2bfloat16(h);
      hdec[(size_t)(t & 1) * 16384 + (size_t)b0 * 512 + jglob] = hb;
      decb[((size_t)b0 * cTM1 + t) * 1024 + 512 + jglob] = hb;
    }
    {
      int b1 = b0 + 16;
      float4 z = z1;
      float4 q = *(const float4*)&Zs[b1][4 * jj];
      z.x += q.x; z.y += q.y; z.z += q.z; z.w += q.w;
      cs1 = sigm(z.y) * cs1 + sigm(z.x) * tanhf(z.z);
      float h = sigm(z.w) * tanhf(cs1);
      __hip_bfloat16 hb = __float2bfloat16(h);
      hdec[(size_t)(t & 1) * 16384 + (size_t)b1 * 512 + jglob] = hb;
      decb[((size_t)b1 * cTM1 + t) * 1024 + 512 + jglob] = hb;
    }
    if (t < cTM1 - 1) {
      z0 = *(const float4*)(yW + ((size_t)((t + 1) * 32 + b0)) * 2048 + c0 + 4 * jj);
      z1 = *(const float4*)(yW + ((size_t)((t + 1) * 32 + b0 + 16)) * 2048 + c0 + 4 * jj);
      gridbar(ctr, flag, 32u, (unsigned)(t + 1));
    }
  }
}

// ---------------- concat builder (bf16 hs sources, zero-padded to 4224 rows) ----------------
__global__ __launch_bounds__(128) void k_cat_bf(const __hip_bfloat16* __restrict__ hs_f,
                                                const __hip_bfloat16* __restrict__ hs_b,
                                                const float* __restrict__ cf,
                                                const float* __restrict__ cb,
                                                __hip_bfloat16* __restrict__ cat) {
  int r = blockIdx.x;
  int tid = threadIdx.x;
  __hip_bfloat16* drow = cat + (size_t)r * 1024 + tid * 8;
  if (r >= 4160) {
    bf16x8 zv = {};
    *(bf16x8*)drow = zv;
    return;
  }
  if (r < 4128) {
    const __hip_bfloat16 *pf, *pb;
    if (r < 4096) {
      int b = r >> 7, s = r & 127;
      pf = hs_f + ((size_t)s * 32 + b) * 512;
      pb = hs_b + ((size_t)s * 32 + b) * 512;
    } else {
      int b = r - 4096;
      pf = hs_f + ((size_t)127 * 32 + b) * 512;   // final fwd h
      pb = hs_b + ((size_t)b) * 512;              // final bwd h (position 0)
    }
    const __hip_bfloat16* s8 = (tid < 64) ? (pf + tid * 8) : (pb + (tid - 64) * 8);
    *(bf16x8*)drow = *(const bf16x8*)s8;
  } else {
    int b = r - 4128;
    const float* s8 = (tid < 64) ? (cf + (size_t)b * 512 + tid * 8)
                                 : (cb + (size_t)b * 512 + (tid - 64) * 8);
    bf16x8 v;
#pragma unroll
    for (int i = 0; i < 8; ++i) v[i] = (__bf16)s8[i];
    *(bf16x8*)drow = v;
  }
}

// ---------------- batched attention over all (b,t): bf16 dec rows ----------------
__global__ __launch_bounds__(256) void k_attn_all(const float* __restrict__ src_h,
                                                  const float* __restrict__ neg,
                                                  __hip_bfloat16* __restrict__ decb) {
  int bid = blockIdx.x;               // 0..2015, XCD-localized by batch
  int xcd = bid & 7, idx = bid >> 3;
  int b = xcd + 8 * (idx / 63);
  int t = idx % 63;
  int tx = threadIdx.x;
  __shared__ float hv[cH];
  __shared__ float part[256];
  __shared__ float sc[cS];
  __shared__ float red[cS];
  __hip_bfloat16* drow = decb + ((size_t)b * cTM1 + t) * (2 * cH);
  hv[tx] = __bfloat162float(drow[cH + tx]);
  hv[tx + 256] = __bfloat162float(drow[cH + tx + 256]);
  __syncthreads();
  {
    int s = tx >> 1, half = tx & 1;
    const float4* sr = (const float4*)(src_h + ((size_t)b * cS + s) * cH + half * 256);
    const float4* hh = (const float4*)(hv + half * 256);
    float acc = 0.f;
#pragma unroll 8
    for (int k = 0; k < 64; ++k) {
      float4 v = sr[k], h4 = hh[k];
      acc += v.x * h4.x + v.y * h4.y + v.z * h4.z + v.w * h4.w;
    }
    part[tx] = acc;
  }
  __syncthreads();
  if (tx < cS) {
    float s0 = part[2 * tx] + part[2 * tx + 1] + neg[b * cS + tx];
    sc[tx] = s0;
    red[tx] = s0;
  }
  __syncthreads();
  for (int off = 64; off >= 1; off >>= 1) {
    if (tx < off) red[tx] = fmaxf(red[tx], red[tx + off]);
    __syncthreads();
  }
  float mx = red[0];
  __syncthreads();
  float e = 0.f;
  if (tx < cS) { e = expf(sc[tx] - mx); red[tx] = e; }
  __syncthreads();
  for (int off = 64; off >= 1; off >>= 1) {
    if (tx < off) red[tx] += red[tx + off];
    __syncthreads();
  }
  float inv = 1.0f / red[0];
  __syncthreads();
  if (tx < cS) sc[tx] = e * inv;
  __syncthreads();
  float a0 = 0.f, a1 = 0.f;
  for (int s = 0; s < cS; ++s) {
    float w = sc[s];
    const float* sr = src_h + ((size_t)b * cS + s) * cH;
    a0 += w * sr[tx];
    a1 += w * sr[tx + 256];
  }
  drow[tx] = __float2bfloat16(a0);
  drow[tx + 256] = __float2bfloat16(a1);
}

extern "C" void kernel_launch(void* const* d_in, const int* in_sizes, int n_in,
                              void* d_out, int out_size, void* d_ws, size_t ws_size,
                              hipStream_t stream) {
  const int* src = (const int*)d_in[0];
  const int* trg = (const int*)d_in[1];
  const float* E_src = (const float*)d_in[2];
  const float* E_trg = (const float*)d_in[3];
  const float* Wf = (const float*)d_in[4];
  const float* Uf = (const float*)d_in[5];
  const float* bf = (const float*)d_in[6];
  const float* Wb = (const float*)d_in[7];
  const float* Ub = (const float*)d_in[8];
  const float* bb = (const float*)d_in[9];
  const float* Wd = (const float*)d_in[10];
  const float* Ud = (const float*)d_in[11];
  const float* bd = (const float*)d_in[12];
  const float* fcW = (const float*)d_in[13];
  const float* fcb = (const float*)d_in[14];
  const float* clsW = (const float*)d_in[15];
  const float* clsb = (const float*)d_in[16];
  float* out = (float*)d_out;
  float* ws = (float*)d_ws;

  // ---- static layout (float offsets), total ~31M floats < R1-proven 36.7M ----
  float* xWf = ws;                                           // 8388608
  float* xWb = ws + 8388608;                                 // -> 16777216
  float* yW = ws + 16777216;                                 // -> 20905984
  __hip_bfloat16* hs_f = (__hip_bfloat16*)(ws + 20905984);   // 1048576 fl
  __hip_bfloat16* hs_b = (__hip_bfloat16*)(ws + 21954560);   // -> 23003136
  float* cf = ws + 23003136;                                 // 16384
  float* cb = ws + 23019520;                                 // 16384
  float* neg = ws + 23035904;                                // -> 23040000
  float* fco = ws + 23040000;                                // 2129920 -> 25169920
  __hip_bfloat16* decb = (__hip_bfloat16*)(ws + 25169920);   // 2048x1024 bf16 = 1048576 fl -> 26218496
  __hip_bfloat16* Utd = (__hip_bfloat16*)(ws + 26218496);    // 524288 fl -> 26742784
  __hip_bfloat16* henc = (__hip_bfloat16*)(ws + 26742784);   // 65536 fl  -> 26808320
  __hip_bfloat16* hdec = (__hip_bfloat16*)(ws + 26808320);   // 32768 fl  -> 26841088
  unsigned* bars = (unsigned*)(ws + 26841088);               // -> 26841152
  float* pool = ws + 26841152;

  // pool transients (pre-encoder)
  __hip_bfloat16* xs_bf = (__hip_bfloat16*)pool;              // 1048576 fl
  __hip_bfloat16* ys_bf = (__hip_bfloat16*)(pool + 1048576);  // 524288 fl
  __hip_bfloat16* Utf = (__hip_bfloat16*)(pool + 1572864);    // 524288 fl
  __hip_bfloat16* Utb = (__hip_bfloat16*)(pool + 2097152);    // 524288 fl
  __hip_bfloat16* Wtfx = (__hip_bfloat16*)(pool + 2621440);   // 524288 fl
  __hip_bfloat16* Wtbx = (__hip_bfloat16*)(pool + 3145728);   // 524288 fl
  __hip_bfloat16* Wtdx = (__hip_bfloat16*)(pool + 3670016);   // 524288 fl
  float* bfx = pool + 4194304;                                // 2048
  float* bbx = pool + 4196352;                                // 2048
  float* bdx = pool + 4198400;                                // 2048
  // post-encoder aliases (xs_bf/ys_bf/Utf/Utb dead)
  __hip_bfloat16* cat_bf = (__hip_bfloat16*)pool;             // 4224x1024 bf16 = 2162688 fl
  __hip_bfloat16* fcWt = (__hip_bfloat16*)(pool + 2162688);   // 262144 fl
  __hip_bfloat16* clsWt = (__hip_bfloat16*)xWf;               // 32000x1024 bf16 (spans xWf+xWb)

  // phase A: embeddings (bf16 direct), weight prep
  k_embed_src<<<4096, 128, 0, stream>>>(src, E_src, xs_bf, neg);
  k_embed_trg<<<2016, 128, 0, stream>>>(trg, E_trg, ys_bf);
  k_f2b<<<64, 256, 0, stream>>>(nullptr, ys_bf + (size_t)2016 * 512, 0, 16384); // zero-pad rows 2016..2047
  k_f2bT<<<dim3(64, 16), 256, 0, stream>>>(Wf, Wtfx, 512, 2048, 1);
  k_f2bT<<<dim3(64, 16), 256, 0, stream>>>(Wb, Wtbx, 512, 2048, 1);
  k_f2bT<<<dim3(64, 16), 256, 0, stream>>>(Wd, Wtdx, 512, 2048, 1);
  k_f2bT<<<dim3(64, 16), 256, 0, stream>>>(Uf, Utf, 512, 2048, 1);
  k_f2bT<<<dim3(64, 16), 256, 0, stream>>>(Ub, Utb, 512, 2048, 1);
  k_f2bT<<<dim3(64, 16), 256, 0, stream>>>(Ud, Utd, 512, 2048, 1);
  k_permb<<<8, 256, 0, stream>>>(bf, bfx);
  k_permb<<<8, 256, 0, stream>>>(bb, bbx);
  k_permb<<<8, 256, 0, stream>>>(bd, bdx);

  // input projections (gate-interleaved columns, bias folded)
  k_bgemm<<<dim3(32, 16), 256, 0, stream>>>(xs_bf, Wtfx, bfx, xWf, 4096, 512, 2048);
  k_bgemm<<<dim3(32, 16), 256, 0, stream>>>(xs_bf, Wtbx, bbx, xWb, 4096, 512, 2048);
  k_bgemm<<<dim3(16, 16), 256, 0, stream>>>(ys_bf, Wtdx, bdx, yW, 2016, 512, 2048);

  // phase B: persistent MFMA encoder (per-dir barriers)
  k_init_bars<<<1, 64, 0, stream>>>(bars);
  k_enc_mfma<<<64, 256, 0, stream>>>(xWf, xWb, Utf, Utb, hs_f, hs_b, henc, cf, cb, bars);

  // phase C: concat + fc projection (bf16 MFMA)
  k_cat_bf<<<4224, 128, 0, stream>>>(hs_f, hs_b, cf, cb, cat_bf);
  k_f2bT<<<dim3(16, 32), 256, 0, stream>>>(fcW, fcWt, 1024, 512, 0);
  k_bgemm<<<dim3(33, 4), 256, 0, stream>>>(cat_bf, fcWt, fcb, fco, 4160, 1024, 512);

  // classifier weight convert (xWf/xWb dead after encoder)
  k_f2bT<<<dim3(1000, 32), 256, 0, stream>>>(clsW, clsWt, 1024, 32000, 0);

  // phase D: persistent MFMA decoder recurrence, then batched attention
  const float* prev_h = fco + (size_t)4096 * 512;
  const float* prev_c = fco + (size_t)4128 * 512;
  k_f2b<<<64, 256, 0, stream>>>(prev_h, hdec + 16384, 16384, 16384);  // h0 -> buf1
  k_dec_mfma<<<32, 256, 0, stream>>>(yW, Utd, prev_c, hdec, decb, bars + 4, bars + 5);
  k_attn_all<<<2016, 256, 0, stream>>>(fco, neg, decb);

  // phase F: classifier (consumes bf16 dec directly; rows 2016..2047 garbage, C-masked)
  k_bgemm<<<dim3(16, 250), 256, 0, stream>>>(decb, clsWt, clsb, out, 2016, 1024, 32000);
}

// Round 7
// 1358.488 us; speedup vs baseline: 6.8356x; 1.2453x over previous
//
#include <hip/hip_runtime.h>
#include <hip/hip_bf16.h>
#include <stdint.h>
#include <string.h>

constexpr int cB = 32, cS = 128, cT = 64, cH = 512, cH4 = 2048, cVT = 32000, cTM1 = 63;

typedef __attribute__((ext_vector_type(8))) __bf16 bf16x8;
typedef __attribute__((ext_vector_type(4))) float f32x4;

__device__ __forceinline__ float sigm(float x) { return 1.0f / (1.0f + expf(-x)); }

// ---- coherence-point (L3) bypass load/store: cross-XCD visible without fences ----
__device__ __forceinline__ bf16x8 sc_load16(const __hip_bfloat16* p) {
  bf16x8 r;
  asm volatile("global_load_dwordx4 %0, %1, off sc0 sc1"
               : "=&v"(r) : "v"(p) : "memory");
  return r;
}
__device__ __forceinline__ void sc_store2(__hip_bfloat16* p, float hval) {
  __hip_bfloat16 hb = __float2bfloat16(hval);
  unsigned short us;
  memcpy(&us, &hb, 2);
  unsigned u = us;
  asm volatile("global_store_short %0, %1, off sc0 sc1"
               :: "v"(p), "v"(u) : "memory");
}

// ---------------- fence-free grid barrier (data coherence via sc0/sc1 path) ----------------
__device__ __forceinline__ void gridbar(unsigned* ctr, unsigned* flag,
                                        unsigned nblk, unsigned gen) {
  asm volatile("s_waitcnt vmcnt(0)" ::: "memory");   // my sc stores reached L3
  __syncthreads();
  if (threadIdx.x == 0) {
    unsigned old = __hip_atomic_fetch_add(ctr, 1u, __ATOMIC_RELAXED,
                                          __HIP_MEMORY_SCOPE_AGENT);
    if (old == gen * nblk - 1u) {
      __hip_atomic_store(flag, gen, __ATOMIC_RELAXED, __HIP_MEMORY_SCOPE_AGENT);
    } else {
      while (__hip_atomic_load(flag, __ATOMIC_RELAXED, __HIP_MEMORY_SCOPE_AGENT) < gen)
        __builtin_amdgcn_s_sleep(2);
    }
  }
  __syncthreads();
}

__global__ __launch_bounds__(64) void k_init_bars(unsigned* p) {
  if (threadIdx.x < 16) p[threadIdx.x] = 0u;
}

// ---------------- embeddings (write bf16 directly) ----------------
__global__ __launch_bounds__(128) void k_embed_src(const int* __restrict__ src,
                                                   const float* __restrict__ E,
                                                   __hip_bfloat16* __restrict__ xs_bf,
                                                   float* __restrict__ neg) {
  int sb = blockIdx.x;            // s*B + b
  int s = sb >> 5, b = sb & 31;
  int tok = src[b * cS + s];
  float4 e = ((const float4*)(E + (size_t)tok * cH))[threadIdx.x];
  __hip_bfloat16* drow = xs_bf + (size_t)sb * cH + threadIdx.x * 4;
  drow[0] = __float2bfloat16(e.x); drow[1] = __float2bfloat16(e.y);
  drow[2] = __float2bfloat16(e.z); drow[3] = __float2bfloat16(e.w);
  if (threadIdx.x == 0) neg[b * cS + s] = (tok == 0) ? -1e9f : 0.0f;
}

__global__ __launch_bounds__(128) void k_embed_trg(const int* __restrict__ trg,
                                                   const float* __restrict__ E,
                                                   __hip_bfloat16* __restrict__ ys_bf) {
  int tb = blockIdx.x;            // t*B + b, t < 63
  int t = tb >> 5, b = tb & 31;
  int tok = trg[b * cT + t];
  float4 e = ((const float4*)(E + (size_t)tok * cH))[threadIdx.x];
  __hip_bfloat16* drow = ys_bf + (size_t)tb * cH + threadIdx.x * 4;
  drow[0] = __float2bfloat16(e.x); drow[1] = __float2bfloat16(e.y);
  drow[2] = __float2bfloat16(e.z); drow[3] = __float2bfloat16(e.w);
}

// ---------------- fp32 -> bf16 elementwise ----------------
__global__ __launch_bounds__(256) void k_f2b(const float* __restrict__ src,
                                             __hip_bfloat16* __restrict__ dst,
                                             int srcN, int dstN) {
  int i = blockIdx.x * 256 + threadIdx.x;
  if (i < dstN) {
    float v = (i < srcN) ? src[i] : 0.0f;
    dst[i] = __float2bfloat16(v);
  }
}

// ---------------- fp32 [K][N] -> bf16 [N][K] transpose-convert ----------------
// gi=1: permute output row n -> (n&511)*4 + (n>>9)  (gate interleave)
__global__ __launch_bounds__(256) void k_f2bT(const float* __restrict__ src,
                                              __hip_bfloat16* __restrict__ dst,
                                              int K, int N, int gi) {
  __shared__ float t[32][33];
  int nt = blockIdx.x * 32, kt = blockIdx.y * 32;
  int c = threadIdx.x & 31, r0 = threadIdx.x >> 5;
#pragma unroll
  for (int i = 0; i < 4; ++i) {
    int r = r0 + i * 8;
    t[r][c] = src[(size_t)(kt + r) * N + nt + c];
  }
  __syncthreads();
#pragma unroll
  for (int i = 0; i < 4; ++i) {
    int row = nt + r0 + i * 8;
    int pr = gi ? (((row & 511) << 2) | (row >> 9)) : row;
    dst[(size_t)pr * K + kt + c] = __float2bfloat16(t[c][r0 + i * 8]);
  }
}

// ---------------- bias gate-interleave: out[j*4+g] = in[g*512+j] ----------------
__global__ __launch_bounds__(256) void k_permb(const float* __restrict__ in,
                                               float* __restrict__ out) {
  int i = blockIdx.x * 256 + threadIdx.x;   // 0..2047
  out[i] = in[(i & 3) * 512 + (i >> 2)];
}

// ---------------- bf16 MFMA GEMM: C[M,N] = A[M,K] @ Bt[N,K]^T + bias ----------------
__global__ __launch_bounds__(256) void k_bgemm(const __hip_bfloat16* __restrict__ A,
                                               const __hip_bfloat16* __restrict__ Bt,
                                               const float* __restrict__ bias,
                                               float* __restrict__ C,
                                               int M, int K, int N) {
  __shared__ __hip_bfloat16 As[128 * 64];
  __shared__ __hip_bfloat16 Bs[128 * 64];
  const int tid = threadIdx.x;
  const int lane = tid & 63;
  const int wave = tid >> 6;
  const int wr = wave >> 1, wc = wave & 1;
  const int bm = blockIdx.x * 128, bn = blockIdx.y * 128;

  f32x4 acc[4][4] = {};

  const int srow = lane >> 3;
  const int scol = (lane & 7) * 8;

  for (int kt = 0; kt < K; kt += 64) {
#pragma unroll
    for (int i = 0; i < 4; ++i) {
      int c = wave * 4 + i;
      const __hip_bfloat16* ga = A + (size_t)(bm + c * 8 + srow) * K + kt + scol;
      __builtin_amdgcn_global_load_lds(
          (const __attribute__((address_space(1))) uint32_t*)ga,
          (__attribute__((address_space(3))) uint32_t*)(As + c * 512), 16, 0, 0);
      const __hip_bfloat16* gb = Bt + (size_t)(bn + c * 8 + srow) * K + kt + scol;
      __builtin_amdgcn_global_load_lds(
          (const __attribute__((address_space(1))) uint32_t*)gb,
          (__attribute__((address_space(3))) uint32_t*)(Bs + c * 512), 16, 0, 0);
    }
    __syncthreads();

#pragma unroll
    for (int kk = 0; kk < 64; kk += 32) {
      const int ko = kk + (lane >> 4) * 8;
      bf16x8 a[4], b[4];
      const int ar = wr * 64 + (lane & 15);
#pragma unroll
      for (int m = 0; m < 4; ++m)
        a[m] = *(const bf16x8*)(As + (size_t)(ar + m * 16) * 64 + ko);
      const int br = wc * 64 + (lane & 15);
#pragma unroll
      for (int n = 0; n < 4; ++n)
        b[n] = *(const bf16x8*)(Bs + (size_t)(br + n * 16) * 64 + ko);
#pragma unroll
      for (int m = 0; m < 4; ++m)
#pragma unroll
        for (int n = 0; n < 4; ++n)
          acc[m][n] = __builtin_amdgcn_mfma_f32_16x16x32_bf16(a[m], b[n], acc[m][n], 0, 0, 0);
    }
    __syncthreads();
  }

#pragma unroll
  for (int m = 0; m < 4; ++m) {
    const int row0 = bm + wr * 64 + m * 16 + (lane >> 4) * 4;
#pragma unroll
    for (int n = 0; n < 4; ++n) {
      const int col = bn + wc * 64 + n * 16 + (lane & 15);
      const float bv = bias[col];
#pragma unroll
      for (int r = 0; r < 4; ++r) {
        const int row = row0 + r;
        if (row < M) C[(size_t)row * N + col] = acc[m][n][r] + bv;
      }
    }
  }
}

// ---------------- persistent MFMA encoder: 64 blocks, per-dir fence-free barriers ----------------
__global__ __launch_bounds__(256, 1) void k_enc_mfma(
    const float* __restrict__ xWf, const float* __restrict__ xWb,
    const __hip_bfloat16* __restrict__ Utf, const __hip_bfloat16* __restrict__ Utb,
    __hip_bfloat16* __restrict__ hs_f, __hip_bfloat16* __restrict__ hs_b,
    __hip_bfloat16* __restrict__ henc,
    float* __restrict__ cf, float* __restrict__ cb,
    unsigned* bars) {
  const int bid = blockIdx.x;
  const int dir = bid >> 5, nb = bid & 31;
  const int c0 = nb * 64;
  const float* xW = dir ? xWb : xWf;
  const __hip_bfloat16* Ut = dir ? Utb : Utf;
  __hip_bfloat16* hs = dir ? hs_b : hs_f;
  __hip_bfloat16* hcur = henc + (size_t)dir * 32768;   // [2][32][512] bf16
  float* cOut = dir ? cb : cf;
  unsigned* ctr = bars + dir * 2;
  unsigned* flag = bars + dir * 2 + 1;

  __shared__ __hip_bfloat16 Hs[32][520];
  __shared__ float Zs[32][68];

  const int tid = threadIdx.x;
  const int lane = tid & 63;
  const int wv = tid >> 6;
  const int wm = wv >> 1, wn = wv & 1;
  const int fr = lane & 15;
  const int fq = lane >> 4;

  // loop-invariant B fragments (U-slice) in registers
  bf16x8 bfrag[2][16];
#pragma unroll
  for (int n = 0; n < 2; ++n)
#pragma unroll
    for (int kk = 0; kk < 16; ++kk)
      bfrag[n][kk] = *(const bf16x8*)(Ut + (size_t)(c0 + (wn * 2 + n) * 16 + fr) * 512 + kk * 32 + fq * 8);

  const int b0 = tid >> 4;        // item0 batch 0..15 (item1 = b0+16)
  const int jj = tid & 15;
  const int jglob = nb * 16 + jj;
  float cs0 = 0.f, cs1 = 0.f;

  const int trow0 = dir ? 127 : 0;
  float4 z0 = *(const float4*)(xW + ((size_t)(trow0 * 32 + b0)) * 2048 + c0 + 4 * jj);
  float4 z1 = *(const float4*)(xW + ((size_t)(trow0 * 32 + b0 + 16)) * 2048 + c0 + 4 * jj);

  for (int t = 0; t < 128; ++t) {
    const int trow = dir ? (127 - t) : t;
    if (t > 0) {
      const __hip_bfloat16* hsrc = hcur + (size_t)((t + 1) & 1) * 16384;
      bf16x8 hr[8];
#pragma unroll
      for (int i = 0; i < 8; ++i) {
        int c = tid + i * 256;                 // 16B chunk id, 0..2047
        hr[i] = sc_load16(hsrc + (size_t)c * 8);
      }
      asm volatile("s_waitcnt vmcnt(0)" ::: "memory");
      __builtin_amdgcn_sched_barrier(0);
#pragma unroll
      for (int i = 0; i < 8; ++i) {
        int c = tid + i * 256;
        int r = c >> 6, cc = (c & 63) * 8;
        *(bf16x8*)&Hs[r][cc] = hr[i];
      }
    }
    // prefetch NEXT step's xW fragment (stays in flight across raw barriers)
    const int tn = (t < 127) ? t + 1 : 127;
    const int ntrow = dir ? (127 - tn) : tn;
    float4 zn0 = *(const float4*)(xW + ((size_t)(ntrow * 32 + b0)) * 2048 + c0 + 4 * jj);
    float4 zn1 = *(const float4*)(xW + ((size_t)(ntrow * 32 + b0 + 16)) * 2048 + c0 + 4 * jj);

    asm volatile("s_waitcnt lgkmcnt(0)" ::: "memory");   // Hs writes visible
    __builtin_amdgcn_s_barrier();
    __builtin_amdgcn_sched_barrier(0);

    if (t > 0) {
      f32x4 acc0 = {}, acc1 = {};
#pragma unroll
      for (int kk = 0; kk < 16; ++kk) {
        bf16x8 a = *(const bf16x8*)&Hs[wm * 16 + fr][kk * 32 + fq * 8];
        acc0 = __builtin_amdgcn_mfma_f32_16x16x32_bf16(a, bfrag[0][kk], acc0, 0, 0, 0);
        acc1 = __builtin_amdgcn_mfma_f32_16x16x32_bf16(a, bfrag[1][kk], acc1, 0, 0, 0);
      }
#pragma unroll
      for (int r = 0; r < 4; ++r) {
        Zs[wm * 16 + fq * 4 + r][(wn * 2 + 0) * 16 + fr] = acc0[r];
        Zs[wm * 16 + fq * 4 + r][(wn * 2 + 1) * 16 + fr] = acc1[r];
      }
    }
    asm volatile("s_waitcnt lgkmcnt(0)" ::: "memory");   // Zs writes visible
    __builtin_amdgcn_s_barrier();
    __builtin_amdgcn_sched_barrier(0);

    {
      float4 z = z0;
      if (t > 0) { float4 q = *(const float4*)&Zs[b0][4 * jj]; z.x += q.x; z.y += q.y; z.z += q.z; z.w += q.w; }
      cs0 = sigm(z.y) * cs0 + sigm(z.x) * tanhf(z.z);
      float h = sigm(z.w) * tanhf(cs0);
      sc_store2(hcur + (size_t)(t & 1) * 16384 + (size_t)b0 * 512 + jglob, h);
      hs[((size_t)trow * 32 + b0) * 512 + jglob] = __float2bfloat16(h);
    }
    {
      int b1 = b0 + 16;
      float4 z = z1;
      if (t > 0) { float4 q = *(const float4*)&Zs[b1][4 * jj]; z.x += q.x; z.y += q.y; z.z += q.z; z.w += q.w; }
      cs1 = sigm(z.y) * cs1 + sigm(z.x) * tanhf(z.z);
      float h = sigm(z.w) * tanhf(cs1);
      sc_store2(hcur + (size_t)(t & 1) * 16384 + (size_t)b1 * 512 + jglob, h);
      hs[((size_t)trow * 32 + b1) * 512 + jglob] = __float2bfloat16(h);
    }
    z0 = zn0; z1 = zn1;
    if (t < 127) gridbar(ctr, flag, 32u, (unsigned)(t + 1));
  }
  cOut[(size_t)b0 * 512 + jglob] = cs0;
  cOut[(size_t)(b0 + 16) * 512 + jglob] = cs1;
}

// ---------------- persistent MFMA decoder recurrence: 32 blocks, 63 steps ----------------
__global__ __launch_bounds__(256, 1) void k_dec_mfma(
    const float* __restrict__ yW, const __hip_bfloat16* __restrict__ Utd,
    const float* __restrict__ prev_c,
    __hip_bfloat16* __restrict__ hdec, __hip_bfloat16* __restrict__ decb,
    unsigned* ctr, unsigned* flag) {
  const int nb = blockIdx.x;
  const int c0 = nb * 64;

  __shared__ __hip_bfloat16 Hs[32][520];
  __shared__ float Zs[32][68];

  const int tid = threadIdx.x;
  const int lane = tid & 63;
  const int wv = tid >> 6;
  const int wm = wv >> 1, wn = wv & 1;
  const int fr = lane & 15;
  const int fq = lane >> 4;

  bf16x8 bfrag[2][16];
#pragma unroll
  for (int n = 0; n < 2; ++n)
#pragma unroll
    for (int kk = 0; kk < 16; ++kk)
      bfrag[n][kk] = *(const bf16x8*)(Utd + (size_t)(c0 + (wn * 2 + n) * 16 + fr) * 512 + kk * 32 + fq * 8);

  const int b0 = tid >> 4;
  const int jj = tid & 15;
  const int jglob = nb * 16 + jj;
  float cs0 = prev_c[(size_t)b0 * 512 + jglob];
  float cs1 = prev_c[(size_t)(b0 + 16) * 512 + jglob];

  float4 z0 = *(const float4*)(yW + ((size_t)b0) * 2048 + c0 + 4 * jj);
  float4 z1 = *(const float4*)(yW + ((size_t)(b0 + 16)) * 2048 + c0 + 4 * jj);

  for (int t = 0; t < cTM1; ++t) {
    const __hip_bfloat16* hsrc = hdec + (size_t)((t + 1) & 1) * 16384;  // t=0: buf1 = prev_h
    {
      bf16x8 hr[8];
#pragma unroll
      for (int i = 0; i < 8; ++i) {
        int c = tid + i * 256;
        hr[i] = sc_load16(hsrc + (size_t)c * 8);
      }
      asm volatile("s_waitcnt vmcnt(0)" ::: "memory");
      __builtin_amdgcn_sched_barrier(0);
#pragma unroll
      for (int i = 0; i < 8; ++i) {
        int c = tid + i * 256;
        int r = c >> 6, cc = (c & 63) * 8;
        *(bf16x8*)&Hs[r][cc] = hr[i];
      }
    }
    const int tn = (t < cTM1 - 1) ? t + 1 : cTM1 - 1;
    float4 zn0 = *(const float4*)(yW + ((size_t)(tn * 32 + b0)) * 2048 + c0 + 4 * jj);
    float4 zn1 = *(const float4*)(yW + ((size_t)(tn * 32 + b0 + 16)) * 2048 + c0 + 4 * jj);

    asm volatile("s_waitcnt lgkmcnt(0)" ::: "memory");
    __builtin_amdgcn_s_barrier();
    __builtin_amdgcn_sched_barrier(0);

    {
      f32x4 acc0 = {}, acc1 = {};
#pragma unroll
      for (int kk = 0; kk < 16; ++kk) {
        bf16x8 a = *(const bf16x8*)&Hs[wm * 16 + fr][kk * 32 + fq * 8];
        acc0 = __builtin_amdgcn_mfma_f32_16x16x32_bf16(a, bfrag[0][kk], acc0, 0, 0, 0);
        acc1 = __builtin_amdgcn_mfma_f32_16x16x32_bf16(a, bfrag[1][kk], acc1, 0, 0, 0);
      }
#pragma unroll
      for (int r = 0; r < 4; ++r) {
        Zs[wm * 16 + fq * 4 + r][(wn * 2 + 0) * 16 + fr] = acc0[r];
        Zs[wm * 16 + fq * 4 + r][(wn * 2 + 1) * 16 + fr] = acc1[r];
      }
    }
    asm volatile("s_waitcnt lgkmcnt(0)" ::: "memory");
    __builtin_amdgcn_s_barrier();
    __builtin_amdgcn_sched_barrier(0);

    {
      float4 z = z0;
      float4 q = *(const float4*)&Zs[b0][4 * jj];
      z.x += q.x; z.y += q.y; z.z += q.z; z.w += q.w;
      cs0 = sigm(z.y) * cs0 + sigm(z.x) * tanhf(z.z);
      float h = sigm(z.w) * tanhf(cs0);
      sc_store2(hdec + (size_t)(t & 1) * 16384 + (size_t)b0 * 512 + jglob, h);
      decb[((size_t)b0 * cTM1 + t) * 1024 + 512 + jglob] = __float2bfloat16(h);
    }
    {
      int b1 = b0 + 16;
      float4 z = z1;
      float4 q = *(const float4*)&Zs[b1][4 * jj];
      z.x += q.x; z.y += q.y; z.z += q.z; z.w += q.w;
      cs1 = sigm(z.y) * cs1 + sigm(z.x) * tanhf(z.z);
      float h = sigm(z.w) * tanhf(cs1);
      sc_store2(hdec + (size_t)(t & 1) * 16384 + (size_t)b1 * 512 + jglob, h);
      decb[((size_t)b1 * cTM1 + t) * 1024 + 512 + jglob] = __float2bfloat16(h);
    }
    z0 = zn0; z1 = zn1;
    if (t < cTM1 - 1) gridbar(ctr, flag, 32u, (unsigned)(t + 1));
  }
}

// ---------------- concat builder (bf16 hs sources, zero-padded to 4224 rows) ----------------
__global__ __launch_bounds__(128) void k_cat_bf(const __hip_bfloat16* __restrict__ hs_f,
                                                const __hip_bfloat16* __restrict__ hs_b,
                                                const float* __restrict__ cf,
                                                const float* __restrict__ cb,
                                                __hip_bfloat16* __restrict__ cat) {
  int r = blockIdx.x;
  int tid = threadIdx.x;
  __hip_bfloat16* drow = cat + (size_t)r * 1024 + tid * 8;
  if (r >= 4160) {
    bf16x8 zv = {};
    *(bf16x8*)drow = zv;
    return;
  }
  if (r < 4128) {
    const __hip_bfloat16 *pf, *pb;
    if (r < 4096) {
      int b = r >> 7, s = r & 127;
      pf = hs_f + ((size_t)s * 32 + b) * 512;
      pb = hs_b + ((size_t)s * 32 + b) * 512;
    } else {
      int b = r - 4096;
      pf = hs_f + ((size_t)127 * 32 + b) * 512;   // final fwd h
      pb = hs_b + ((size_t)b) * 512;              // final bwd h (position 0)
    }
    const __hip_bfloat16* s8 = (tid < 64) ? (pf + tid * 8) : (pb + (tid - 64) * 8);
    *(bf16x8*)drow = *(const bf16x8*)s8;
  } else {
    int b = r - 4128;
    const float* s8 = (tid < 64) ? (cf + (size_t)b * 512 + tid * 8)
                                 : (cb + (size_t)b * 512 + (tid - 64) * 8);
    bf16x8 v;
#pragma unroll
    for (int i = 0; i < 8; ++i) v[i] = (__bf16)s8[i];
    *(bf16x8*)drow = v;
  }
}

// ---------------- batched attention over all (b,t): bf16 dec rows ----------------
__global__ __launch_bounds__(256) void k_attn_all(const float* __restrict__ src_h,
                                                  const float* __restrict__ neg,
                                                  __hip_bfloat16* __restrict__ decb) {
  int bid = blockIdx.x;               // 0..2015, XCD-localized by batch
  int xcd = bid & 7, idx = bid >> 3;
  int b = xcd + 8 * (idx / 63);
  int t = idx % 63;
  int tx = threadIdx.x;
  __shared__ float hv[cH];
  __shared__ float part[256];
  __shared__ float sc[cS];
  __shared__ float red[cS];
  __hip_bfloat16* drow = decb + ((size_t)b * cTM1 + t) * (2 * cH);
  hv[tx] = __bfloat162float(drow[cH + tx]);
  hv[tx + 256] = __bfloat162float(drow[cH + tx + 256]);
  __syncthreads();
  {
    int s = tx >> 1, half = tx & 1;
    const float4* sr = (const float4*)(src_h + ((size_t)b * cS + s) * cH + half * 256);
    const float4* hh = (const float4*)(hv + half * 256);
    float acc = 0.f;
#pragma unroll 8
    for (int k = 0; k < 64; ++k) {
      float4 v = sr[k], h4 = hh[k];
      acc += v.x * h4.x + v.y * h4.y + v.z * h4.z + v.w * h4.w;
    }
    part[tx] = acc;
  }
  __syncthreads();
  if (tx < cS) {
    float s0 = part[2 * tx] + part[2 * tx + 1] + neg[b * cS + tx];
    sc[tx] = s0;
    red[tx] = s0;
  }
  __syncthreads();
  for (int off = 64; off >= 1; off >>= 1) {
    if (tx < off) red[tx] = fmaxf(red[tx], red[tx + off]);
    __syncthreads();
  }
  float mx = red[0];
  __syncthreads();
  float e = 0.f;
  if (tx < cS) { e = expf(sc[tx] - mx); red[tx] = e; }
  __syncthreads();
  for (int off = 64; off >= 1; off >>= 1) {
    if (tx < off) red[tx] += red[tx + off];
    __syncthreads();
  }
  float inv = 1.0f / red[0];
  __syncthreads();
  if (tx < cS) sc[tx] = e * inv;
  __syncthreads();
  float a0 = 0.f, a1 = 0.f;
  for (int s = 0; s < cS; ++s) {
    float w = sc[s];
    const float* sr = src_h + ((size_t)b * cS + s) * cH;
    a0 += w * sr[tx];
    a1 += w * sr[tx + 256];
  }
  drow[tx] = __float2bfloat16(a0);
  drow[tx + 256] = __float2bfloat16(a1);
}

extern "C" void kernel_launch(void* const* d_in, const int* in_sizes, int n_in,
                              void* d_out, int out_size, void* d_ws, size_t ws_size,
                              hipStream_t stream) {
  const int* src = (const int*)d_in[0];
  const int* trg = (const int*)d_in[1];
  const float* E_src = (const float*)d_in[2];
  const float* E_trg = (const float*)d_in[3];
  const float* Wf = (const float*)d_in[4];
  const float* Uf = (const float*)d_in[5];
  const float* bf = (const float*)d_in[6];
  const float* Wb = (const float*)d_in[7];
  const float* Ub = (const float*)d_in[8];
  const float* bb = (const float*)d_in[9];
  const float* Wd = (const float*)d_in[10];
  const float* Ud = (const float*)d_in[11];
  const float* bd = (const float*)d_in[12];
  const float* fcW = (const float*)d_in[13];
  const float* fcb = (const float*)d_in[14];
  const float* clsW = (const float*)d_in[15];
  const float* clsb = (const float*)d_in[16];
  float* out = (float*)d_out;
  float* ws = (float*)d_ws;

  // ---- static layout (float offsets), total ~31M floats < R1-proven 36.7M ----
  float* xWf = ws;                                           // 8388608
  float* xWb = ws + 8388608;                                 // -> 16777216
  float* yW = ws + 16777216;                                 // -> 20905984
  __hip_bfloat16* hs_f = (__hip_bfloat16*)(ws + 20905984);   // 1048576 fl
  __hip_bfloat16* hs_b = (__hip_bfloat16*)(ws + 21954560);   // -> 23003136
  float* cf = ws + 23003136;                                 // 16384
  float* cb = ws + 23019520;                                 // 16384
  float* neg = ws + 23035904;                                // -> 23040000
  float* fco = ws + 23040000;                                // 2129920 -> 25169920
  __hip_bfloat16* decb = (__hip_bfloat16*)(ws + 25169920);   // 2048x1024 bf16 -> 26218496
  __hip_bfloat16* Utd = (__hip_bfloat16*)(ws + 26218496);    // 524288 fl -> 26742784
  __hip_bfloat16* henc = (__hip_bfloat16*)(ws + 26742784);   // 65536 fl  -> 26808320
  __hip_bfloat16* hdec = (__hip_bfloat16*)(ws + 26808320);   // 32768 fl  -> 26841088
  unsigned* bars = (unsigned*)(ws + 26841088);               // -> 26841152
  float* pool = ws + 26841152;

  // pool transients (pre-encoder)
  __hip_bfloat16* xs_bf = (__hip_bfloat16*)pool;              // 1048576 fl
  __hip_bfloat16* ys_bf = (__hip_bfloat16*)(pool + 1048576);  // 524288 fl
  __hip_bfloat16* Utf = (__hip_bfloat16*)(pool + 1572864);    // 524288 fl
  __hip_bfloat16* Utb = (__hip_bfloat16*)(pool + 2097152);    // 524288 fl
  __hip_bfloat16* Wtfx = (__hip_bfloat16*)(pool + 2621440);   // 524288 fl
  __hip_bfloat16* Wtbx = (__hip_bfloat16*)(pool + 3145728);   // 524288 fl
  __hip_bfloat16* Wtdx = (__hip_bfloat16*)(pool + 3670016);   // 524288 fl
  float* bfx = pool + 4194304;                                // 2048
  float* bbx = pool + 4196352;                                // 2048
  float* bdx = pool + 4198400;                                // 2048
  // post-encoder aliases (xs_bf/ys_bf/Utf/Utb dead)
  __hip_bfloat16* cat_bf = (__hip_bfloat16*)pool;             // 4224x1024 bf16
  __hip_bfloat16* fcWt = (__hip_bfloat16*)(pool + 2162688);   // 262144 fl
  __hip_bfloat16* clsWt = (__hip_bfloat16*)xWf;               // 32000x1024 bf16 (spans xWf+xWb)

  // phase A: embeddings (bf16 direct), weight prep
  k_embed_src<<<4096, 128, 0, stream>>>(src, E_src, xs_bf, neg);
  k_embed_trg<<<2016, 128, 0, stream>>>(trg, E_trg, ys_bf);
  k_f2b<<<64, 256, 0, stream>>>(nullptr, ys_bf + (size_t)2016 * 512, 0, 16384); // zero-pad rows 2016..2047
  k_f2bT<<<dim3(64, 16), 256, 0, stream>>>(Wf, Wtfx, 512, 2048, 1);
  k_f2bT<<<dim3(64, 16), 256, 0, stream>>>(Wb, Wtbx, 512, 2048, 1);
  k_f2bT<<<dim3(64, 16), 256, 0, stream>>>(Wd, Wtdx, 512, 2048, 1);
  k_f2bT<<<dim3(64, 16), 256, 0, stream>>>(Uf, Utf, 512, 2048, 1);
  k_f2bT<<<dim3(64, 16), 256, 0, stream>>>(Ub, Utb, 512, 2048, 1);
  k_f2bT<<<dim3(64, 16), 256, 0, stream>>>(Ud, Utd, 512, 2048, 1);
  k_permb<<<8, 256, 0, stream>>>(bf, bfx);
  k_permb<<<8, 256, 0, stream>>>(bb, bbx);
  k_permb<<<8, 256, 0, stream>>>(bd, bdx);

  // input projections (gate-interleaved columns, bias folded)
  k_bgemm<<<dim3(32, 16), 256, 0, stream>>>(xs_bf, Wtfx, bfx, xWf, 4096, 512, 2048);
  k_bgemm<<<dim3(32, 16), 256, 0, stream>>>(xs_bf, Wtbx, bbx, xWb, 4096, 512, 2048);
  k_bgemm<<<dim3(16, 16), 256, 0, stream>>>(ys_bf, Wtdx, bdx, yW, 2016, 512, 2048);

  // phase B: persistent MFMA encoder (fence-free barriers, sc-coherent h exchange)
  k_init_bars<<<1, 64, 0, stream>>>(bars);
  k_enc_mfma<<<64, 256, 0, stream>>>(xWf, xWb, Utf, Utb, hs_f, hs_b, henc, cf, cb, bars);

  // phase C: concat + fc projection (bf16 MFMA)
  k_cat_bf<<<4224, 128, 0, stream>>>(hs_f, hs_b, cf, cb, cat_bf);
  k_f2bT<<<dim3(16, 32), 256, 0, stream>>>(fcW, fcWt, 1024, 512, 0);
  k_bgemm<<<dim3(33, 4), 256, 0, stream>>>(cat_bf, fcWt, fcb, fco, 4160, 1024, 512);

  // classifier weight convert (xWf/xWb dead after encoder)
  k_f2bT<<<dim3(1000, 32), 256, 0, stream>>>(clsW, clsWt, 1024, 32000, 0);

  // phase D: persistent MFMA decoder recurrence, then batched attention
  const float* prev_h = fco + (size_t)4096 * 512;
  const float* prev_c = fco + (size_t)4128 * 512;
  k_f2b<<<64, 256, 0, stream>>>(prev_h, hdec + 16384, 16384, 16384);  // h0 -> buf1
  k_dec_mfma<<<32, 256, 0, stream>>>(yW, Utd, prev_c, hdec, decb, bars + 4, bars + 5);
  k_attn_all<<<2016, 256, 0, stream>>>(fco, neg, decb);

  // phase F: classifier (consumes bf16 dec directly; rows 2016..2047 garbage, C-masked)
  k_bgemm<<<dim3(16, 250), 256, 0, stream>>>(decb, clsWt, clsb, out, 2016, 1024, 32000);
}